// Round 4
// baseline (12800.121 us; speedup 1.0000x reference)
//
#include <hip/hip_runtime.h>
#include <hip/hip_bf16.h>
#include <cstddef>

#define BB 256
#define TT 224
#define II 224
#define HH 1024
#define OO 4
#define NBLK 256

typedef __attribute__((ext_vector_type(8))) short short8;   // 8 bf16 (4 VGPRs)
typedef __attribute__((ext_vector_type(4))) float f32x4;    // MFMA accumulator

// ---------------------------------------------------------------- utility
__global__ void zero_kernel(float* __restrict__ p, int n) {
    int i = blockIdx.x * blockDim.x + threadIdx.x;
    if (i < n) p[i] = 0.f;
}

// split fp32 -> bf16 hi + bf16 lo (v ~= hi + lo, residual ~2^-17 rel)
__global__ __launch_bounds__(256) void split_hi_lo(
    const float* __restrict__ src, __hip_bfloat16* __restrict__ hi,
    __hip_bfloat16* __restrict__ lo, int n4)
{
    struct bfx4 { __hip_bfloat16 v[4]; };
    const int stride = gridDim.x * blockDim.x;
    for (int i = blockIdx.x * blockDim.x + threadIdx.x; i < n4; i += stride) {
        float4 s = ((const float4*)src)[i];
        float vv[4] = {s.x, s.y, s.z, s.w};
        bfx4 h, l;
        #pragma unroll
        for (int j = 0; j < 4; ++j) {
            __hip_bfloat16 hb = __float2bfloat16(vv[j]);
            h.v[j] = hb;
            l.v[j] = __float2bfloat16(vv[j] - __bfloat162float(hb));
        }
        ((bfx4*)hi)[i] = h;
        ((bfx4*)lo)[i] = l;
    }
}

#define MFMA3R(m, n, AH, AL, BH, BL)                                                  \
    acc[m][n] = __builtin_amdgcn_mfma_f32_16x16x32_bf16(AH, BH, acc[m][n], 0, 0, 0);  \
    acc[m][n] = __builtin_amdgcn_mfma_f32_16x16x32_bf16(AH, BL, acc[m][n], 0, 0, 0);  \
    acc[m][n] = __builtin_amdgcn_mfma_f32_16x16x32_bf16(AL, BH, acc[m][n], 0, 0, 0);

// ---------------------------------------------------------------- persistent RNN
// 256 WGs (1 per CU, cooperative) x 256 thr (4 waves). WG owns a 32x32 output
// tile for ALL 224 timesteps. W_hh K-slice (8 kb x 2 cols x hi/lo = 128 VGPR)
// and W_ih slice (32 VGPR) live in registers for the whole sequence.
// Grid barrier: monotonic agent-scope atomic + __threadfence (wbL2/inv) since
// per-XCD L2s are not coherent for the h exchange.
__global__ __launch_bounds__(256, 1) void rnn_persistent(
    const __hip_bfloat16* __restrict__ xh,   const __hip_bfloat16* __restrict__ xl,
    const __hip_bfloat16* __restrict__ wihh, const __hip_bfloat16* __restrict__ wihl,
    const __hip_bfloat16* __restrict__ whhh, const __hip_bfloat16* __restrict__ whhl,
    __hip_bfloat16* __restrict__ h_h0, __hip_bfloat16* __restrict__ h_l0,
    __hip_bfloat16* __restrict__ h_h1, __hip_bfloat16* __restrict__ h_l1,
    const float* __restrict__ b_ih, const float* __restrict__ b_hh,
    float* __restrict__ h32, unsigned* __restrict__ barcnt)
{
    __shared__ float red[4][32][33];   // +1 pad: conflict-free partial-sum buffer

    const int tid   = threadIdx.x;
    const int wv    = tid >> 6;        // wave 0..3 (K-split)
    const int lane  = tid & 63;
    const int row16 = lane & 15;
    const int kblk  = lane >> 4;       // 0..3

    const int lid = blockIdx.x;        // 0..255
    const int q   = lid & 7;           // XCD
    const int j   = lid >> 3;
    const int r0  = (j >> 2) * 32;                 // batch-row tile 0..7
    const int c0  = ((q << 2) | (j & 3)) * 32;     // h-col tile 0..31

    // ---- load register-resident weight fragments (once) ----
    // W_hh: wave wv owns K range [wv*256, wv*256+256) -> 8 kblocks of 32
    short8 whhHi[8][2], whhLo[8][2];
    #pragma unroll
    for (int n = 0; n < 2; ++n) {
        const size_t bb = (size_t)(c0 + n * 16 + row16) * HH + wv * 256 + kblk * 8;
        #pragma unroll
        for (int kb = 0; kb < 8; ++kb) {
            whhHi[kb][n] = *(const short8*)(whhh + bb + kb * 32);
            whhLo[kb][n] = *(const short8*)(whhl + bb + kb * 32);
        }
    }
    // W_ih: wave wv owns x-kblocks {wv*2, wv*2+1} ∩ [0,7)
    short8 wihHi[2][2], wihLo[2][2];
    #pragma unroll
    for (int n = 0; n < 2; ++n) {
        const size_t bb = (size_t)(c0 + n * 16 + row16) * II + kblk * 8;
        #pragma unroll
        for (int kb = 0; kb < 2; ++kb) {
            const int gx = wv * 2 + kb;
            if (gx < 7) {
                wihHi[kb][n] = *(const short8*)(wihh + bb + gx * 32);
                wihLo[kb][n] = *(const short8*)(wihl + bb + gx * 32);
            } else {
                wihHi[kb][n] = short8{0,0,0,0,0,0,0,0};
                wihLo[kb][n] = short8{0,0,0,0,0,0,0,0};
            }
        }
    }

    // hoisted epilogue constants (wave's quadrant: m=wv>>1, n=wv&1)
    const int mq = wv >> 1, nq = wv & 1;
    const int lc = nq * 16 + row16;
    const int cg = c0 + lc;
    const float biasv = b_ih[cg] + b_hh[cg];

    // hoisted A-fragment bases (k part varies per kb)
    const size_t ha0 = (size_t)(r0 + row16) * HH + wv * 256 + kblk * 8;
    const size_t ha1 = (size_t)(r0 + 16 + row16) * HH + wv * 256 + kblk * 8;

    for (int t = 0; t < TT; ++t) {
        const __hip_bfloat16* hhp = (t & 1) ? h_h1 : h_h0;
        const __hip_bfloat16* hlp = (t & 1) ? h_l1 : h_l0;
        __hip_bfloat16* hhn = (t & 1) ? h_h0 : h_h1;
        __hip_bfloat16* hln = (t & 1) ? h_l0 : h_l1;

        f32x4 acc[2][2] = {};

        // ---- input-projection kblocks (wave's 2, predicated) ----
        {
            const size_t xa0 = ((size_t)(r0 + row16) * TT + t) * II + kblk * 8;
            const size_t xa1 = ((size_t)(r0 + 16 + row16) * TT + t) * II + kblk * 8;
            #pragma unroll
            for (int kb = 0; kb < 2; ++kb) {
                const int gx = wv * 2 + kb;
                if (gx < 7) {
                    const int k = gx * 32;
                    short8 ah0 = *(const short8*)(xh + xa0 + k);
                    short8 ah1 = *(const short8*)(xh + xa1 + k);
                    short8 al0 = *(const short8*)(xl + xa0 + k);
                    short8 al1 = *(const short8*)(xl + xa1 + k);
                    MFMA3R(0, 0, ah0, al0, wihHi[kb][0], wihLo[kb][0])
                    MFMA3R(0, 1, ah0, al0, wihHi[kb][1], wihLo[kb][1])
                    MFMA3R(1, 0, ah1, al1, wihHi[kb][0], wihLo[kb][0])
                    MFMA3R(1, 1, ah1, al1, wihHi[kb][1], wihLo[kb][1])
                }
            }
        }

        // ---- recurrent kblocks (wave's 8, W resident) ----
        #pragma unroll
        for (int kb = 0; kb < 8; ++kb) {
            const int k = kb * 32;
            short8 ah0 = *(const short8*)(hhp + ha0 + k);
            short8 ah1 = *(const short8*)(hhp + ha1 + k);
            short8 al0 = *(const short8*)(hlp + ha0 + k);
            short8 al1 = *(const short8*)(hlp + ha1 + k);
            MFMA3R(0, 0, ah0, al0, whhHi[kb][0], whhLo[kb][0])
            MFMA3R(0, 1, ah0, al0, whhHi[kb][1], whhLo[kb][1])
            MFMA3R(1, 0, ah1, al1, whhHi[kb][0], whhLo[kb][0])
            MFMA3R(1, 1, ah1, al1, whhHi[kb][1], whhLo[kb][1])
        }

        // ---- cross-wave K reduction through LDS ----
        #pragma unroll
        for (int m = 0; m < 2; ++m)
            #pragma unroll
            for (int n = 0; n < 2; ++n)
                #pragma unroll
                for (int jj = 0; jj < 4; ++jj)
                    red[wv][m * 16 + kblk * 4 + jj][n * 16 + row16] = acc[m][n][jj];
        __syncthreads();

        // ---- epilogue: each wave finalizes its 16x16 quadrant ----
        #pragma unroll
        for (int jj = 0; jj < 4; ++jj) {
            const int lr = mq * 16 + kblk * 4 + jj;
            float v = red[0][lr][lc] + red[1][lr][lc] + red[2][lr][lc] + red[3][lr][lc] + biasv;
            v = tanhf(v);
            const size_t o = (size_t)(r0 + lr) * HH + cg;
            __hip_bfloat16 hb = __float2bfloat16(v);
            hhn[o] = hb;
            hln[o] = __float2bfloat16(v - __bfloat162float(hb));
            if (t == TT - 1) h32[o] = v;
        }

        // ---- grid barrier (skip after last step) ----
        if (t != TT - 1) {
            __threadfence();           // agent release: flush h writes to coherent point
            __syncthreads();
            if (tid == 0) {
                __hip_atomic_fetch_add(barcnt, 1u, __ATOMIC_ACQ_REL, __HIP_MEMORY_SCOPE_AGENT);
                const unsigned tgt = (unsigned)(t + 1) * (unsigned)NBLK;
                while (__hip_atomic_load(barcnt, __ATOMIC_ACQUIRE, __HIP_MEMORY_SCOPE_AGENT) < tgt)
                    __builtin_amdgcn_s_sleep(1);
            }
            __syncthreads();
            __threadfence();           // agent acquire: invalidate stale L2 lines for h
        }
    }
}

// ---------------------------------------------------------------- per-step fallback (R2 proven path)
__global__ __launch_bounds__(256) void rnn_step_mfma2(
    const __hip_bfloat16* __restrict__ xh,   const __hip_bfloat16* __restrict__ xl,
    const __hip_bfloat16* __restrict__ wihh, const __hip_bfloat16* __restrict__ wihl,
    const __hip_bfloat16* __restrict__ whhh, const __hip_bfloat16* __restrict__ whhl,
    const __hip_bfloat16* __restrict__ hhp,  const __hip_bfloat16* __restrict__ hlp,
    const float* __restrict__ b_ih, const float* __restrict__ b_hh,
    __hip_bfloat16* __restrict__ hhn, __hip_bfloat16* __restrict__ hln,
    float* __restrict__ h32, int t)
{
    __shared__ float red[4][32][33];
    const int tid   = threadIdx.x;
    const int wv    = tid >> 6;
    const int lane  = tid & 63;
    const int row16 = lane & 15;
    const int kblk  = lane >> 4;
    const int lid = blockIdx.x + blockIdx.y * gridDim.x;
    const int q   = lid & 7;
    const int j   = lid >> 3;
    const int r0  = (j >> 2) * 32;
    const int c0  = ((q << 2) | (j & 3)) * 32;

    f32x4 acc[2][2] = {};
    const int kb_beg = wv * 10;
    const int kb_end = (kb_beg + 10 < 39) ? kb_beg + 10 : 39;
    {
        const int xb_beg = (kb_beg < 7) ? kb_beg : 7;
        const int xb_end = (kb_end < 7) ? kb_end : 7;
        const size_t a0 = ((size_t)(r0 + row16) * TT + t) * II + kblk * 8;
        const size_t a1 = ((size_t)(r0 + 16 + row16) * TT + t) * II + kblk * 8;
        const size_t b0 = (size_t)(c0 + row16) * II + kblk * 8;
        const size_t b1 = (size_t)(c0 + 16 + row16) * II + kblk * 8;
        for (int kb = xb_beg; kb < xb_end; ++kb) {
            const int k = kb * 32;
            short8 ah0 = *(const short8*)(xh + a0 + k);
            short8 ah1 = *(const short8*)(xh + a1 + k);
            short8 al0 = *(const short8*)(xl + a0 + k);
            short8 al1 = *(const short8*)(xl + a1 + k);
            short8 bh0 = *(const short8*)(wihh + b0 + k);
            short8 bh1 = *(const short8*)(wihh + b1 + k);
            short8 bl0 = *(const short8*)(wihl + b0 + k);
            short8 bl1 = *(const short8*)(wihl + b1 + k);
            MFMA3R(0, 0, ah0, al0, bh0, bl0)
            MFMA3R(0, 1, ah0, al0, bh1, bl1)
            MFMA3R(1, 0, ah1, al1, bh0, bl0)
            MFMA3R(1, 1, ah1, al1, bh1, bl1)
        }
    }
    {
        const int hb_beg = ((kb_beg > 7) ? kb_beg : 7) - 7;
        const int hb_end = kb_end - 7;
        const size_t a0 = (size_t)(r0 + row16) * HH + kblk * 8;
        const size_t a1 = (size_t)(r0 + 16 + row16) * HH + kblk * 8;
        const size_t b0 = (size_t)(c0 + row16) * HH + kblk * 8;
        const size_t b1 = (size_t)(c0 + 16 + row16) * HH + kblk * 8;
        #pragma unroll 5
        for (int kb = hb_beg; kb < hb_end; ++kb) {
            const int k = kb * 32;
            short8 ah0 = *(const short8*)(hhp + a0 + k);
            short8 ah1 = *(const short8*)(hhp + a1 + k);
            short8 al0 = *(const short8*)(hlp + a0 + k);
            short8 al1 = *(const short8*)(hlp + a1 + k);
            short8 bh0 = *(const short8*)(whhh + b0 + k);
            short8 bh1 = *(const short8*)(whhh + b1 + k);
            short8 bl0 = *(const short8*)(whhl + b0 + k);
            short8 bl1 = *(const short8*)(whhl + b1 + k);
            MFMA3R(0, 0, ah0, al0, bh0, bl0)
            MFMA3R(0, 1, ah0, al0, bh1, bl1)
            MFMA3R(1, 0, ah1, al1, bh0, bl0)
            MFMA3R(1, 1, ah1, al1, bh1, bl1)
        }
    }
    #pragma unroll
    for (int m = 0; m < 2; ++m)
        #pragma unroll
        for (int n = 0; n < 2; ++n)
            #pragma unroll
            for (int jj = 0; jj < 4; ++jj)
                red[wv][m * 16 + kblk * 4 + jj][n * 16 + row16] = acc[m][n][jj];
    __syncthreads();
    {
        const int m = wv >> 1, n = wv & 1;
        const int lc = n * 16 + row16;
        const int c  = c0 + lc;
        const float bias = b_ih[c] + b_hh[c];
        #pragma unroll
        for (int jj = 0; jj < 4; ++jj) {
            const int lr = m * 16 + kblk * 4 + jj;
            float v = red[0][lr][lc] + red[1][lr][lc] + red[2][lr][lc] + red[3][lr][lc] + bias;
            v = tanhf(v);
            const size_t o = (size_t)(r0 + lr) * HH + c;
            __hip_bfloat16 hb = __float2bfloat16(v);
            hhn[o] = hb;
            hln[o] = __float2bfloat16(v - __bfloat162float(hb));
            if (t == TT - 1) h32[o] = v;
        }
    }
}

// ---------------------------------------------------------------- FC
__global__ __launch_bounds__(256) void fc_kernel(
    const float* __restrict__ h, const float* __restrict__ W_fc,
    const float* __restrict__ b_fc, float* __restrict__ out)
{
    const int b = blockIdx.x;
    const int tid = threadIdx.x;
    float p[OO] = {0.f, 0.f, 0.f, 0.f};
    for (int k = tid; k < HH; k += 256) {
        float hv = h[(size_t)b * HH + k];
        #pragma unroll
        for (int o = 0; o < OO; ++o) p[o] += hv * W_fc[(size_t)o * HH + k];
    }
    #pragma unroll
    for (int off = 32; off > 0; off >>= 1) {
        #pragma unroll
        for (int o = 0; o < OO; ++o) p[o] += __shfl_down(p[o], off, 64);
    }
    __shared__ float red[4][OO];
    const int wave = tid >> 6, lane = tid & 63;
    if (lane == 0) {
        #pragma unroll
        for (int o = 0; o < OO; ++o) red[wave][o] = p[o];
    }
    __syncthreads();
    if (tid < OO) {
        float s = red[0][tid] + red[1][tid] + red[2][tid] + red[3][tid] + b_fc[tid];
        out[b * OO + tid] = s;
    }
}

// ---------------------------------------------------------------- launch
extern "C" void kernel_launch(void* const* d_in, const int* in_sizes, int n_in,
                              void* d_out, int out_size, void* d_ws, size_t ws_size,
                              hipStream_t stream) {
    const float* x    = (const float*)d_in[0];
    const float* W_ih = (const float*)d_in[1];
    const float* W_hh = (const float*)d_in[2];
    const float* b_ih = (const float*)d_in[3];
    const float* b_hh = (const float*)d_in[4];
    const float* W_fc = (const float*)d_in[5];
    const float* b_fc = (const float*)d_in[6];
    float* out = (float*)d_out;

    // ws layout (bytes)
    const size_t SZ_X   = (size_t)BB * TT * II * 2;
    const size_t SZ_WIH = (size_t)HH * II * 2;
    const size_t SZ_WHH = (size_t)HH * HH * 2;
    const size_t SZ_H   = (size_t)BB * HH * 2;
    const size_t OFF_XH   = 0;
    const size_t OFF_XL   = OFF_XH + SZ_X;
    const size_t OFF_WIHH = OFF_XL + SZ_X;
    const size_t OFF_WIHL = OFF_WIHH + SZ_WIH;
    const size_t OFF_WHHH = OFF_WIHL + SZ_WIH;
    const size_t OFF_WHHL = OFF_WHHH + SZ_WHH;
    const size_t OFF_HH0  = OFF_WHHL + SZ_WHH;
    const size_t OFF_HL0  = OFF_HH0 + SZ_H;
    const size_t OFF_HH1  = OFF_HL0 + SZ_H;
    const size_t OFF_HL1  = OFF_HH1 + SZ_H;
    const size_t OFF_H32  = OFF_HL1 + SZ_H;
    const size_t OFF_CNT  = OFF_H32 + (size_t)BB * HH * 4;
    const size_t NEED     = OFF_CNT + 256;

    char* ws = (char*)d_ws;

    if (ws_size >= NEED) {
        __hip_bfloat16* xhp   = (__hip_bfloat16*)(ws + OFF_XH);
        __hip_bfloat16* xlp   = (__hip_bfloat16*)(ws + OFF_XL);
        __hip_bfloat16* wihhp = (__hip_bfloat16*)(ws + OFF_WIHH);
        __hip_bfloat16* wihlp = (__hip_bfloat16*)(ws + OFF_WIHL);
        __hip_bfloat16* whhhp = (__hip_bfloat16*)(ws + OFF_WHHH);
        __hip_bfloat16* whhlp = (__hip_bfloat16*)(ws + OFF_WHHL);
        __hip_bfloat16* hh0 = (__hip_bfloat16*)(ws + OFF_HH0);
        __hip_bfloat16* hl0 = (__hip_bfloat16*)(ws + OFF_HL0);
        __hip_bfloat16* hh1 = (__hip_bfloat16*)(ws + OFF_HH1);
        __hip_bfloat16* hl1 = (__hip_bfloat16*)(ws + OFF_HL1);
        float* h32 = (float*)(ws + OFF_H32);
        unsigned* cnt = (unsigned*)(ws + OFF_CNT);

        // per-call precision splits
        split_hi_lo<<<1024, 256, 0, stream>>>(x, xhp, xlp, (BB * TT * II) / 4);
        split_hi_lo<<<128, 256, 0, stream>>>(W_ih, wihhp, wihlp, (HH * II) / 4);
        split_hi_lo<<<512, 256, 0, stream>>>(W_hh, whhhp, whhlp, (HH * HH) / 4);
        // zero h0 planes (hh0+hl0 contiguous) and barrier counter
        zero_kernel<<<(int)((2 * SZ_H / 4 + 255) / 256), 256, 0, stream>>>((float*)(ws + OFF_HH0), (int)(2 * SZ_H / 4));
        zero_kernel<<<1, 64, 0, stream>>>((float*)cnt, 64);

        const float* bihp = b_ih;
        const float* bhhp = b_hh;
        void* args[] = {
            (void*)&xhp, (void*)&xlp, (void*)&wihhp, (void*)&wihlp,
            (void*)&whhhp, (void*)&whhlp,
            (void*)&hh0, (void*)&hl0, (void*)&hh1, (void*)&hl1,
            (void*)&bihp, (void*)&bhhp, (void*)&h32, (void*)&cnt
        };
        hipError_t e = hipLaunchCooperativeKernel((void*)rnn_persistent,
                                                  dim3(NBLK), dim3(256), args, 0, stream);
        if (e != hipSuccess) {
            // fallback: proven per-step loop
            for (int t = 0; t < TT; ++t) {
                const int p = t & 1;
                rnn_step_mfma2<<<dim3(8, 32), 256, 0, stream>>>(
                    xhp, xlp, wihhp, wihlp, whhhp, whhlp,
                    (p ? hh1 : hh0), (p ? hl1 : hl0), b_ih, b_hh,
                    (p ? hh0 : hh1), (p ? hl0 : hl1), h32, t);
            }
        }
        fc_kernel<<<BB, 256, 0, stream>>>(h32, W_fc, b_fc, out);
    }
    // (ws too small is not expected: NEED ~62 MB, observed ws ~268 MB)
}

// Round 5
// 11970.741 us; speedup vs baseline: 1.0693x; 1.0693x over previous
//
#include <hip/hip_runtime.h>
#include <hip/hip_bf16.h>
#include <cstddef>

#define BB 256
#define TT 224
#define II 224
#define HH 1024
#define OO 4
#define NBLK 256

typedef __attribute__((ext_vector_type(8))) short short8;   // 8 bf16 (4 VGPRs)
typedef __attribute__((ext_vector_type(4))) float f32x4;    // MFMA accumulator

// ---------------------------------------------------------------- utility
__global__ void zero_kernel(float* __restrict__ p, int n) {
    int i = blockIdx.x * blockDim.x + threadIdx.x;
    if (i < n) p[i] = 0.f;
}

// split fp32 -> bf16 hi + bf16 lo (v ~= hi + lo, residual ~2^-17 rel)
__global__ __launch_bounds__(256) void split_hi_lo(
    const float* __restrict__ src, __hip_bfloat16* __restrict__ hi,
    __hip_bfloat16* __restrict__ lo, int n4)
{
    struct bfx4 { __hip_bfloat16 v[4]; };
    const int stride = gridDim.x * blockDim.x;
    for (int i = blockIdx.x * blockDim.x + threadIdx.x; i < n4; i += stride) {
        float4 s = ((const float4*)src)[i];
        float vv[4] = {s.x, s.y, s.z, s.w};
        bfx4 h, l;
        #pragma unroll
        for (int j = 0; j < 4; ++j) {
            __hip_bfloat16 hb = __float2bfloat16(vv[j]);
            h.v[j] = hb;
            l.v[j] = __float2bfloat16(vv[j] - __bfloat162float(hb));
        }
        ((bfx4*)hi)[i] = h;
        ((bfx4*)lo)[i] = l;
    }
}

#define MFMA3R(m, n, AH, AL, BH, BL)                                                  \
    acc[m][n] = __builtin_amdgcn_mfma_f32_16x16x32_bf16(AH, BH, acc[m][n], 0, 0, 0);  \
    acc[m][n] = __builtin_amdgcn_mfma_f32_16x16x32_bf16(AH, BL, acc[m][n], 0, 0, 0);  \
    acc[m][n] = __builtin_amdgcn_mfma_f32_16x16x32_bf16(AL, BH, acc[m][n], 0, 0, 0);

// ---------------------------------------------------------------- persistent RNN
// 256 WGs (1 per CU, cooperative) x 256 thr (4 waves). WG owns a 32x32 output
// tile for ALL 224 timesteps; W_hh/W_ih K-slices live in VGPRs for the whole
// sequence. Grid barrier per step: one release fence + relaxed add + RELAXED
// spin-poll (NO per-poll acquire -> no L2-invalidate storm) + one acquire fence.
__global__ __launch_bounds__(256, 1) void rnn_persistent(
    const __hip_bfloat16* __restrict__ xh,   const __hip_bfloat16* __restrict__ xl,
    const __hip_bfloat16* __restrict__ wihh, const __hip_bfloat16* __restrict__ wihl,
    const __hip_bfloat16* __restrict__ whhh, const __hip_bfloat16* __restrict__ whhl,
    __hip_bfloat16* __restrict__ h_h0, __hip_bfloat16* __restrict__ h_l0,
    __hip_bfloat16* __restrict__ h_h1, __hip_bfloat16* __restrict__ h_l1,
    const float* __restrict__ b_ih, const float* __restrict__ b_hh,
    float* __restrict__ h32, unsigned* __restrict__ barcnt)
{
    __shared__ float red[4][32][34];   // stride 34: 136k%32=8 -> 2 lanes/bank = free

    const int tid   = threadIdx.x;
    const int wv    = tid >> 6;        // wave 0..3 (K-split)
    const int lane  = tid & 63;
    const int row16 = lane & 15;
    const int kblk  = lane >> 4;       // 0..3

    const int lid = blockIdx.x;        // 0..255
    const int q   = lid & 7;           // XCD heuristic
    const int j   = lid >> 3;
    const int r0  = (j >> 2) * 32;                 // batch-row tile 0..7
    const int c0  = ((q << 2) | (j & 3)) * 32;     // h-col tile 0..31

    // ---- load register-resident weight fragments (once) ----
    short8 whhHi[8][2], whhLo[8][2];
    #pragma unroll
    for (int n = 0; n < 2; ++n) {
        const size_t bb = (size_t)(c0 + n * 16 + row16) * HH + wv * 256 + kblk * 8;
        #pragma unroll
        for (int kb = 0; kb < 8; ++kb) {
            whhHi[kb][n] = *(const short8*)(whhh + bb + kb * 32);
            whhLo[kb][n] = *(const short8*)(whhl + bb + kb * 32);
        }
    }
    short8 wihHi[2][2], wihLo[2][2];
    #pragma unroll
    for (int n = 0; n < 2; ++n) {
        const size_t bb = (size_t)(c0 + n * 16 + row16) * II + kblk * 8;
        #pragma unroll
        for (int kb = 0; kb < 2; ++kb) {
            const int gx = wv * 2 + kb;
            if (gx < 7) {
                wihHi[kb][n] = *(const short8*)(wihh + bb + gx * 32);
                wihLo[kb][n] = *(const short8*)(wihl + bb + gx * 32);
            } else {
                wihHi[kb][n] = short8{0,0,0,0,0,0,0,0};
                wihLo[kb][n] = short8{0,0,0,0,0,0,0,0};
            }
        }
    }

    // hoisted epilogue constants (wave's quadrant: m=wv>>1, n=wv&1)
    const int mq = wv >> 1, nq = wv & 1;
    const int lc = nq * 16 + row16;
    const int cg = c0 + lc;
    const float biasv = b_ih[cg] + b_hh[cg];

    const size_t ha0 = (size_t)(r0 + row16) * HH + wv * 256 + kblk * 8;
    const size_t ha1 = (size_t)(r0 + 16 + row16) * HH + wv * 256 + kblk * 8;

    for (int t = 0; t < TT; ++t) {
        const __hip_bfloat16* hhp = (t & 1) ? h_h1 : h_h0;
        const __hip_bfloat16* hlp = (t & 1) ? h_l1 : h_l0;
        __hip_bfloat16* hhn = (t & 1) ? h_h0 : h_h1;
        __hip_bfloat16* hln = (t & 1) ? h_l0 : h_l1;

        f32x4 acc[2][2] = {};

        // ---- input-projection kblocks (wave's 2, predicated) ----
        {
            const size_t xa0 = ((size_t)(r0 + row16) * TT + t) * II + kblk * 8;
            const size_t xa1 = ((size_t)(r0 + 16 + row16) * TT + t) * II + kblk * 8;
            #pragma unroll
            for (int kb = 0; kb < 2; ++kb) {
                const int gx = wv * 2 + kb;
                if (gx < 7) {
                    const int k = gx * 32;
                    short8 ah0 = *(const short8*)(xh + xa0 + k);
                    short8 ah1 = *(const short8*)(xh + xa1 + k);
                    short8 al0 = *(const short8*)(xl + xa0 + k);
                    short8 al1 = *(const short8*)(xl + xa1 + k);
                    MFMA3R(0, 0, ah0, al0, wihHi[kb][0], wihLo[kb][0])
                    MFMA3R(0, 1, ah0, al0, wihHi[kb][1], wihLo[kb][1])
                    MFMA3R(1, 0, ah1, al1, wihHi[kb][0], wihLo[kb][0])
                    MFMA3R(1, 1, ah1, al1, wihHi[kb][1], wihLo[kb][1])
                }
            }
        }

        // ---- recurrent kblocks (wave's 8, W register-resident) ----
        #pragma unroll
        for (int kb = 0; kb < 8; ++kb) {
            const int k = kb * 32;
            short8 ah0 = *(const short8*)(hhp + ha0 + k);
            short8 ah1 = *(const short8*)(hhp + ha1 + k);
            short8 al0 = *(const short8*)(hlp + ha0 + k);
            short8 al1 = *(const short8*)(hlp + ha1 + k);
            MFMA3R(0, 0, ah0, al0, whhHi[kb][0], whhLo[kb][0])
            MFMA3R(0, 1, ah0, al0, whhHi[kb][1], whhLo[kb][1])
            MFMA3R(1, 0, ah1, al1, whhHi[kb][0], whhLo[kb][0])
            MFMA3R(1, 1, ah1, al1, whhHi[kb][1], whhLo[kb][1])
        }

        // ---- cross-wave K reduction through LDS ----
        #pragma unroll
        for (int m = 0; m < 2; ++m)
            #pragma unroll
            for (int n = 0; n < 2; ++n)
                #pragma unroll
                for (int jj = 0; jj < 4; ++jj)
                    red[wv][m * 16 + kblk * 4 + jj][n * 16 + row16] = acc[m][n][jj];
        __syncthreads();

        // ---- epilogue: each wave finalizes its 16x16 quadrant ----
        #pragma unroll
        for (int jj = 0; jj < 4; ++jj) {
            const int lr = mq * 16 + kblk * 4 + jj;
            float v = red[0][lr][lc] + red[1][lr][lc] + red[2][lr][lc] + red[3][lr][lc] + biasv;
            v = tanhf(v);
            const size_t o = (size_t)(r0 + lr) * HH + cg;
            __hip_bfloat16 hb = __float2bfloat16(v);
            hhn[o] = hb;
            hln[o] = __float2bfloat16(v - __bfloat162float(hb));
            if (t == TT - 1) h32[o] = v;
        }

        // ---- grid barrier (skip after last step) ----
        if (t != TT - 1) {
            __threadfence();           // ONE release: drain + wbL2
            __syncthreads();
            if (tid == 0) {
                __hip_atomic_fetch_add(barcnt, 1u, __ATOMIC_RELAXED, __HIP_MEMORY_SCOPE_AGENT);
                const unsigned tgt = (unsigned)(t + 1) * (unsigned)NBLK;
                // RELAXED poll: no buffer_inv per iteration
                while (__hip_atomic_load(barcnt, __ATOMIC_RELAXED, __HIP_MEMORY_SCOPE_AGENT) < tgt)
                    __builtin_amdgcn_s_sleep(8);
            }
            __syncthreads();
            __threadfence();           // ONE acquire: invalidate stale L1/L2 lines
        }
    }
}

// ---------------------------------------------------------------- per-step fallback (R2 proven path)
__global__ __launch_bounds__(256) void rnn_step_mfma2(
    const __hip_bfloat16* __restrict__ xh,   const __hip_bfloat16* __restrict__ xl,
    const __hip_bfloat16* __restrict__ wihh, const __hip_bfloat16* __restrict__ wihl,
    const __hip_bfloat16* __restrict__ whhh, const __hip_bfloat16* __restrict__ whhl,
    const __hip_bfloat16* __restrict__ hhp,  const __hip_bfloat16* __restrict__ hlp,
    const float* __restrict__ b_ih, const float* __restrict__ b_hh,
    __hip_bfloat16* __restrict__ hhn, __hip_bfloat16* __restrict__ hln,
    float* __restrict__ h32, int t)
{
    __shared__ float red[4][32][34];
    const int tid   = threadIdx.x;
    const int wv    = tid >> 6;
    const int lane  = tid & 63;
    const int row16 = lane & 15;
    const int kblk  = lane >> 4;
    const int lid = blockIdx.x + blockIdx.y * gridDim.x;
    const int q   = lid & 7;
    const int j   = lid >> 3;
    const int r0  = (j >> 2) * 32;
    const int c0  = ((q << 2) | (j & 3)) * 32;

    f32x4 acc[2][2] = {};
    const int kb_beg = wv * 10;
    const int kb_end = (kb_beg + 10 < 39) ? kb_beg + 10 : 39;
    {
        const int xb_beg = (kb_beg < 7) ? kb_beg : 7;
        const int xb_end = (kb_end < 7) ? kb_end : 7;
        const size_t a0 = ((size_t)(r0 + row16) * TT + t) * II + kblk * 8;
        const size_t a1 = ((size_t)(r0 + 16 + row16) * TT + t) * II + kblk * 8;
        const size_t b0 = (size_t)(c0 + row16) * II + kblk * 8;
        const size_t b1 = (size_t)(c0 + 16 + row16) * II + kblk * 8;
        for (int kb = xb_beg; kb < xb_end; ++kb) {
            const int k = kb * 32;
            short8 ah0 = *(const short8*)(xh + a0 + k);
            short8 ah1 = *(const short8*)(xh + a1 + k);
            short8 al0 = *(const short8*)(xl + a0 + k);
            short8 al1 = *(const short8*)(xl + a1 + k);
            short8 bh0 = *(const short8*)(wihh + b0 + k);
            short8 bh1 = *(const short8*)(wihh + b1 + k);
            short8 bl0 = *(const short8*)(wihl + b0 + k);
            short8 bl1 = *(const short8*)(wihl + b1 + k);
            MFMA3R(0, 0, ah0, al0, bh0, bl0)
            MFMA3R(0, 1, ah0, al0, bh1, bl1)
            MFMA3R(1, 0, ah1, al1, bh0, bl0)
            MFMA3R(1, 1, ah1, al1, bh1, bl1)
        }
    }
    {
        const int hb_beg = ((kb_beg > 7) ? kb_beg : 7) - 7;
        const int hb_end = kb_end - 7;
        const size_t a0 = (size_t)(r0 + row16) * HH + kblk * 8;
        const size_t a1 = (size_t)(r0 + 16 + row16) * HH + kblk * 8;
        const size_t b0 = (size_t)(c0 + row16) * HH + kblk * 8;
        const size_t b1 = (size_t)(c0 + 16 + row16) * HH + kblk * 8;
        #pragma unroll 5
        for (int kb = hb_beg; kb < hb_end; ++kb) {
            const int k = kb * 32;
            short8 ah0 = *(const short8*)(hhp + a0 + k);
            short8 ah1 = *(const short8*)(hhp + a1 + k);
            short8 al0 = *(const short8*)(hlp + a0 + k);
            short8 al1 = *(const short8*)(hlp + a1 + k);
            short8 bh0 = *(const short8*)(whhh + b0 + k);
            short8 bh1 = *(const short8*)(whhh + b1 + k);
            short8 bl0 = *(const short8*)(whhl + b0 + k);
            short8 bl1 = *(const short8*)(whhl + b1 + k);
            MFMA3R(0, 0, ah0, al0, bh0, bl0)
            MFMA3R(0, 1, ah0, al0, bh1, bl1)
            MFMA3R(1, 0, ah1, al1, bh0, bl0)
            MFMA3R(1, 1, ah1, al1, bh1, bl1)
        }
    }
    #pragma unroll
    for (int m = 0; m < 2; ++m)
        #pragma unroll
        for (int n = 0; n < 2; ++n)
            #pragma unroll
            for (int jj = 0; jj < 4; ++jj)
                red[wv][m * 16 + kblk * 4 + jj][n * 16 + row16] = acc[m][n][jj];
    __syncthreads();
    {
        const int m = wv >> 1, n = wv & 1;
        const int lc = n * 16 + row16;
        const int c  = c0 + lc;
        const float bias = b_ih[c] + b_hh[c];
        #pragma unroll
        for (int jj = 0; jj < 4; ++jj) {
            const int lr = m * 16 + kblk * 4 + jj;
            float v = red[0][lr][lc] + red[1][lr][lc] + red[2][lr][lc] + red[3][lr][lc] + bias;
            v = tanhf(v);
            const size_t o = (size_t)(r0 + lr) * HH + c;
            __hip_bfloat16 hb = __float2bfloat16(v);
            hhn[o] = hb;
            hln[o] = __float2bfloat16(v - __bfloat162float(hb));
            if (t == TT - 1) h32[o] = v;
        }
    }
}

// ---------------------------------------------------------------- FC
__global__ __launch_bounds__(256) void fc_kernel(
    const float* __restrict__ h, const float* __restrict__ W_fc,
    const float* __restrict__ b_fc, float* __restrict__ out)
{
    const int b = blockIdx.x;
    const int tid = threadIdx.x;
    float p[OO] = {0.f, 0.f, 0.f, 0.f};
    for (int k = tid; k < HH; k += 256) {
        float hv = h[(size_t)b * HH + k];
        #pragma unroll
        for (int o = 0; o < OO; ++o) p[o] += hv * W_fc[(size_t)o * HH + k];
    }
    #pragma unroll
    for (int off = 32; off > 0; off >>= 1) {
        #pragma unroll
        for (int o = 0; o < OO; ++o) p[o] += __shfl_down(p[o], off, 64);
    }
    __shared__ float red[4][OO];
    const int wave = tid >> 6, lane = tid & 63;
    if (lane == 0) {
        #pragma unroll
        for (int o = 0; o < OO; ++o) red[wave][o] = p[o];
    }
    __syncthreads();
    if (tid < OO) {
        float s = red[0][tid] + red[1][tid] + red[2][tid] + red[3][tid] + b_fc[tid];
        out[b * OO + tid] = s;
    }
}

// ---------------------------------------------------------------- launch
extern "C" void kernel_launch(void* const* d_in, const int* in_sizes, int n_in,
                              void* d_out, int out_size, void* d_ws, size_t ws_size,
                              hipStream_t stream) {
    const float* x    = (const float*)d_in[0];
    const float* W_ih = (const float*)d_in[1];
    const float* W_hh = (const float*)d_in[2];
    const float* b_ih = (const float*)d_in[3];
    const float* b_hh = (const float*)d_in[4];
    const float* W_fc = (const float*)d_in[5];
    const float* b_fc = (const float*)d_in[6];
    float* out = (float*)d_out;

    // ws layout (bytes)
    const size_t SZ_X   = (size_t)BB * TT * II * 2;
    const size_t SZ_WIH = (size_t)HH * II * 2;
    const size_t SZ_WHH = (size_t)HH * HH * 2;
    const size_t SZ_H   = (size_t)BB * HH * 2;
    const size_t OFF_XH   = 0;
    const size_t OFF_XL   = OFF_XH + SZ_X;
    const size_t OFF_WIHH = OFF_XL + SZ_X;
    const size_t OFF_WIHL = OFF_WIHH + SZ_WIH;
    const size_t OFF_WHHH = OFF_WIHL + SZ_WIH;
    const size_t OFF_WHHL = OFF_WHHH + SZ_WHH;
    const size_t OFF_HH0  = OFF_WHHL + SZ_WHH;
    const size_t OFF_HL0  = OFF_HH0 + SZ_H;
    const size_t OFF_HH1  = OFF_HL0 + SZ_H;
    const size_t OFF_HL1  = OFF_HH1 + SZ_H;
    const size_t OFF_H32  = OFF_HL1 + SZ_H;
    const size_t OFF_CNT  = OFF_H32 + (size_t)BB * HH * 4;
    const size_t NEED     = OFF_CNT + 256;

    char* ws = (char*)d_ws;

    if (ws_size >= NEED) {
        __hip_bfloat16* xhp   = (__hip_bfloat16*)(ws + OFF_XH);
        __hip_bfloat16* xlp   = (__hip_bfloat16*)(ws + OFF_XL);
        __hip_bfloat16* wihhp = (__hip_bfloat16*)(ws + OFF_WIHH);
        __hip_bfloat16* wihlp = (__hip_bfloat16*)(ws + OFF_WIHL);
        __hip_bfloat16* whhhp = (__hip_bfloat16*)(ws + OFF_WHHH);
        __hip_bfloat16* whhlp = (__hip_bfloat16*)(ws + OFF_WHHL);
        __hip_bfloat16* hh0 = (__hip_bfloat16*)(ws + OFF_HH0);
        __hip_bfloat16* hl0 = (__hip_bfloat16*)(ws + OFF_HL0);
        __hip_bfloat16* hh1 = (__hip_bfloat16*)(ws + OFF_HH1);
        __hip_bfloat16* hl1 = (__hip_bfloat16*)(ws + OFF_HL1);
        float* h32 = (float*)(ws + OFF_H32);
        unsigned* cnt = (unsigned*)(ws + OFF_CNT);

        // per-call precision splits
        split_hi_lo<<<1024, 256, 0, stream>>>(x, xhp, xlp, (BB * TT * II) / 4);
        split_hi_lo<<<128, 256, 0, stream>>>(W_ih, wihhp, wihlp, (HH * II) / 4);
        split_hi_lo<<<512, 256, 0, stream>>>(W_hh, whhhp, whhlp, (HH * HH) / 4);
        // zero h0 planes (hh0+hl0 contiguous) and barrier counter
        zero_kernel<<<(int)((2 * SZ_H / 4 + 255) / 256), 256, 0, stream>>>((float*)(ws + OFF_HH0), (int)(2 * SZ_H / 4));
        zero_kernel<<<1, 64, 0, stream>>>((float*)cnt, 64);

        const float* bihp = b_ih;
        const float* bhhp = b_hh;
        void* args[] = {
            (void*)&xhp, (void*)&xlp, (void*)&wihhp, (void*)&wihlp,
            (void*)&whhhp, (void*)&whhlp,
            (void*)&hh0, (void*)&hl0, (void*)&hh1, (void*)&hl1,
            (void*)&bihp, (void*)&bhhp, (void*)&h32, (void*)&cnt
        };
        hipError_t e = hipLaunchCooperativeKernel((void*)rnn_persistent,
                                                  dim3(NBLK), dim3(256), args, 0, stream);
        if (e != hipSuccess) {
            // fallback: proven per-step loop (R2, 2.95 ms)
            for (int t = 0; t < TT; ++t) {
                const int p = t & 1;
                rnn_step_mfma2<<<dim3(8, 32), 256, 0, stream>>>(
                    xhp, xlp, wihhp, wihlp, whhhp, whhlp,
                    (p ? hh1 : hh0), (p ? hl1 : hl0), b_ih, b_hh,
                    (p ? hh0 : hh1), (p ? hl0 : hl1), h32, t);
            }
        }
        fc_kernel<<<BB, 256, 0, stream>>>(h32, W_fc, b_fc, out);
    }
}

// Round 6
// 2016.319 us; speedup vs baseline: 6.3483x; 5.9369x over previous
//
#include <hip/hip_runtime.h>
#include <hip/hip_bf16.h>
#include <cstddef>
#include <cstdint>

#define BB 256
#define TT 224
#define II 224
#define HH 1024
#define OO 4

typedef __attribute__((ext_vector_type(8))) short short8;   // 8 bf16 (4 VGPRs)
typedef __attribute__((ext_vector_type(4))) float f32x4;    // MFMA accumulator
typedef unsigned short ushort_t;

// ---------------------------------------------------------------- helpers
__device__ __forceinline__ unsigned short bfbits(float v) {
    __hip_bfloat16 b = __float2bfloat16(v);
    union { __hip_bfloat16 b; unsigned short u; } cv; cv.b = b; return cv.u;
}
__device__ __forceinline__ float bffloat(unsigned short u) {
    union { unsigned short u; __hip_bfloat16 b; } cv; cv.u = u; return __bfloat162float(cv.b);
}

// system-scope (bypass L1+L2, meet at MALL) memory ops
__device__ __forceinline__ void ld128_sys(short8& d, const void* p) {
    asm volatile("global_load_dwordx4 %0, %1, off sc0 sc1" : "=v"(d) : "v"(p) : "memory");
}
__device__ __forceinline__ void st16_sys(void* p, unsigned v) {
    asm volatile("global_store_short %0, %1, off sc0 sc1" :: "v"(p), "v"(v) : "memory");
}
__device__ __forceinline__ void stflag(unsigned* p, unsigned v) {
    asm volatile("global_store_dword %0, %1, off sc0 sc1" :: "v"(p), "v"(v) : "memory");
}
__device__ __forceinline__ unsigned ldflag(const unsigned* p) {
    unsigned v;
    asm volatile("global_load_dword %0, %1, off sc0 sc1\n\ts_waitcnt vmcnt(0)"
                 : "=v"(v) : "v"(p) : "memory");
    return v;
}
__device__ __forceinline__ void wait_vm0() {
    asm volatile("s_waitcnt vmcnt(0)" ::: "memory");
    __builtin_amdgcn_sched_barrier(0);
}

#define MFMA3R(m, n, AH, AL, BH, BL)                                                  \
    acc[m][n] = __builtin_amdgcn_mfma_f32_16x16x32_bf16(AH, BH, acc[m][n], 0, 0, 0);  \
    acc[m][n] = __builtin_amdgcn_mfma_f32_16x16x32_bf16(AH, BL, acc[m][n], 0, 0, 0);  \
    acc[m][n] = __builtin_amdgcn_mfma_f32_16x16x32_bf16(AL, BH, acc[m][n], 0, 0, 0);

// swizzled LDS read of W_hh slice: plane 0=hi,1=lo; col 0..31 local; k global 0..1023
__device__ __forceinline__ short8 wread(const char* lds, int plane, int col, int k) {
    int byte = (col << 11) + (k << 1);
    byte ^= ((col & 7) << 4);
    return *(const short8*)(lds + (plane << 16) + byte);
}

// ---------------------------------------------------------------- utility kernels
__global__ void zero_kernel(float* __restrict__ p, int n) {
    int i = blockIdx.x * blockDim.x + threadIdx.x;
    if (i < n) p[i] = 0.f;
}

__global__ __launch_bounds__(256) void split_hi_lo(
    const float* __restrict__ src, ushort_t* __restrict__ hi,
    ushort_t* __restrict__ lo, int n4)
{
    struct u4 { ushort_t v[4]; };
    const int stride = gridDim.x * blockDim.x;
    for (int i = blockIdx.x * blockDim.x + threadIdx.x; i < n4; i += stride) {
        float4 s = ((const float4*)src)[i];
        float vv[4] = {s.x, s.y, s.z, s.w};
        u4 h, l;
        #pragma unroll
        for (int j = 0; j < 4; ++j) {
            unsigned short hb = bfbits(vv[j]);
            h.v[j] = hb;
            l.v[j] = bfbits(vv[j] - bffloat(hb));
        }
        ((u4*)hi)[i] = h;
        ((u4*)lo)[i] = l;
    }
}

// ---------------------------------------------------------------- x-projection GEMM
// xproj[m][c] with m = t*256 + b : xproj = x W_ih^T + b_ih (hi/lo split precision)
// grid (1792, 32), 1 wave per 32x32 tile, K = 224.
__global__ __launch_bounds__(64) void xproj_gemm(
    const float* __restrict__ x, const ushort_t* __restrict__ wihh,
    const ushort_t* __restrict__ wihl, const float* __restrict__ b_ih,
    float* __restrict__ xproj)
{
    const int lane = threadIdx.x;
    const int row16 = lane & 15;
    const int kblk = lane >> 4;
    const int m0 = blockIdx.x * 32;
    const int c0 = blockIdx.y * 32;
    const int tt = m0 >> 8;        // 8 row-tiles per t, never crosses t
    const int brow = m0 & 255;

    f32x4 acc[2][2] = {};
    const size_t xa0 = ((size_t)(brow + row16) * TT + tt) * II;
    const size_t xa1 = ((size_t)(brow + 16 + row16) * TT + tt) * II;
    const size_t wb0 = (size_t)(c0 + row16) * II;
    const size_t wb1 = (size_t)(c0 + 16 + row16) * II;

    #pragma unroll
    for (int kb = 0; kb < 7; ++kb) {
        const int k = kb * 32 + kblk * 8;
        short8 ah0, al0, ah1, al1;
        {
            const float* p = x + xa0 + k;
            #pragma unroll
            for (int j2 = 0; j2 < 8; ++j2) {
                float v = p[j2];
                unsigned short hb = bfbits(v);
                ah0[j2] = (short)hb;
                al0[j2] = (short)bfbits(v - bffloat(hb));
            }
            p = x + xa1 + k;
            #pragma unroll
            for (int j2 = 0; j2 < 8; ++j2) {
                float v = p[j2];
                unsigned short hb = bfbits(v);
                ah1[j2] = (short)hb;
                al1[j2] = (short)bfbits(v - bffloat(hb));
            }
        }
        short8 bh0 = *(const short8*)(wihh + wb0 + k);
        short8 bh1 = *(const short8*)(wihh + wb1 + k);
        short8 bl0 = *(const short8*)(wihl + wb0 + k);
        short8 bl1 = *(const short8*)(wihl + wb1 + k);
        MFMA3R(0, 0, ah0, al0, bh0, bl0)
        MFMA3R(0, 1, ah0, al0, bh1, bl1)
        MFMA3R(1, 0, ah1, al1, bh0, bl0)
        MFMA3R(1, 1, ah1, al1, bh1, bl1)
    }
    #pragma unroll
    for (int n = 0; n < 2; ++n) {
        const int c = c0 + n * 16 + row16;
        const float bi = b_ih[c];
        #pragma unroll
        for (int m = 0; m < 2; ++m)
            #pragma unroll
            for (int jj = 0; jj < 4; ++jj) {
                const int mr = m0 + m * 16 + kblk * 4 + jj;
                xproj[(size_t)mr * HH + c] = acc[m][n][jj] + bi;
            }
    }
}

// ---------------------------------------------------------------- persistent RNN (R6)
// 256 WGs (cooperative, 1/CU) x 256 thr. Group g = lid&7 owns batch rows 32g..32g+31;
// its 32 blocks (cb = lid>>3) col-split H. h exchange is GROUP-LOCAL through the MALL
// (sc0 sc1 loads/stores bypass L1/L2) -> NO fences, W_hh LDS + xproj L2 never disturbed.
// Barrier: per-group 32-flag poll; 2-plane ping-pong makes distance-1 overlap safe.
__global__ __launch_bounds__(256, 1) void rnn_persist2(
    const float* __restrict__ xproj,
    const ushort_t* __restrict__ whhh, const ushort_t* __restrict__ whhl,
    ushort_t* hAh, ushort_t* hAl, ushort_t* hBh, ushort_t* hBl,
    const float* __restrict__ b_hh, float* __restrict__ h32,
    unsigned* __restrict__ flags)
{
    __shared__ short8 wlds8[8192];        // 128 KiB: W_hh slice hi+lo, swizzled
    __shared__ float red[4][32][34];
    char* lds = (char*)wlds8;

    const int tid = threadIdx.x;
    const int wv = tid >> 6, lane = tid & 63;
    const int row16 = lane & 15, kblk = lane >> 4;
    const int lid = blockIdx.x;
    const int rb = lid & 7;               // row-group (XCD-aligned under %8 placement)
    const int cb = lid >> 3;
    const int r0 = rb * 32, c0 = cb * 32;

    // ---- stage W_hh slice into swizzled LDS (once) ----
    #pragma unroll
    for (int it = 0; it < 32; ++it) {
        const int u = tid + it * 256;     // 0..8191 16B-units
        const int plane = u >> 12;
        const int rem = u & 4095;
        const int col = rem >> 7;         // 128 units per col-row
        const int k8 = rem & 127;
        int byte = (col << 11) + (k8 << 4);
        byte ^= ((col & 7) << 4);
        const ushort_t* src = (plane ? whhl : whhh) + (size_t)(c0 + col) * HH + k8 * 8;
        *(short8*)(lds + (plane << 16) + byte) = *(const short8*)src;
    }
    __syncthreads();

    const int mq = wv >> 1, nq = wv & 1;  // wave's output quadrant
    const int lc = nq * 16 + row16;
    const int cg = c0 + lc;
    const float biasv = b_hh[cg];

    const size_t ha0 = (size_t)(r0 + row16) * HH + wv * 256 + kblk * 8;
    const size_t ha1 = (size_t)(r0 + 16 + row16) * HH + wv * 256 + kblk * 8;

    for (int t = 0; t < TT; ++t) {
        const ushort_t* hph = (t & 1) ? hBh : hAh;
        const ushort_t* hpl = (t & 1) ? hBl : hAl;
        ushort_t* hnh = (t & 1) ? hAh : hBh;
        ushort_t* hnl = (t & 1) ? hAl : hBl;

        // xproj prefetch (4 fp32 per thread, L2-cached; consumed in epilogue)
        float xp[4];
        #pragma unroll
        for (int jj = 0; jj < 4; ++jj)
            xp[jj] = xproj[((size_t)t * BB + (r0 + mq * 16 + kblk * 4 + jj)) * HH + cg];

        // h prefetch: all 32 fragments, system scope (MALL), then one drain
        short8 fh0[8], fh1[8], fl0[8], fl1[8];
        #pragma unroll
        for (int kb = 0; kb < 8; ++kb) {
            ld128_sys(fh0[kb], hph + ha0 + kb * 32);
            ld128_sys(fh1[kb], hph + ha1 + kb * 32);
            ld128_sys(fl0[kb], hpl + ha0 + kb * 32);
            ld128_sys(fl1[kb], hpl + ha1 + kb * 32);
        }
        wait_vm0();

        f32x4 acc[2][2] = {};
        #pragma unroll
        for (int kb = 0; kb < 8; ++kb) {
            const int k = wv * 256 + kb * 32 + kblk * 8;
            #pragma unroll
            for (int n = 0; n < 2; ++n) {
                const short8 bh = wread(lds, 0, n * 16 + row16, k);
                const short8 bl = wread(lds, 1, n * 16 + row16, k);
                MFMA3R(0, n, fh0[kb], fl0[kb], bh, bl)
                MFMA3R(1, n, fh1[kb], fl1[kb], bh, bl)
            }
        }

        // cross-wave K reduction
        #pragma unroll
        for (int m = 0; m < 2; ++m)
            #pragma unroll
            for (int n = 0; n < 2; ++n)
                #pragma unroll
                for (int jj = 0; jj < 4; ++jj)
                    red[wv][m * 16 + kblk * 4 + jj][n * 16 + row16] = acc[m][n][jj];
        __syncthreads();

        // epilogue: wave's 16x16 quadrant; bias = b_hh only (b_ih folded into xproj)
        #pragma unroll
        for (int jj = 0; jj < 4; ++jj) {
            const int lr = mq * 16 + kblk * 4 + jj;
            float v = red[0][lr][lc] + red[1][lr][lc] + red[2][lr][lc] + red[3][lr][lc]
                      + xp[jj] + biasv;
            v = tanhf(v);
            const size_t o = (size_t)(r0 + lr) * HH + cg;
            const unsigned short hb = bfbits(v);
            st16_sys(hnh + o, (unsigned)hb);
            st16_sys(hnl + o, (unsigned)bfbits(v - bffloat(hb)));
            if (t == TT - 1) h32[o] = v;
        }

        wait_vm0();            // h stores acked at MALL
        __syncthreads();       // all waves' stores done

        if (t != TT - 1) {
            if (tid == 0) stflag(flags + (size_t)lid * 16, (unsigned)(t + 1));
            if (tid < 64) {    // wave 0 polls the group's 32 flags (lanes duplicated)
                const unsigned want = (unsigned)(t + 1);
                const unsigned* fp = flags + (size_t)(rb + 8 * (tid & 31)) * 16;
                while (true) {
                    unsigned v = ldflag(fp);
                    if (__ballot(v >= want) == ~0ull) break;
                    __builtin_amdgcn_s_sleep(1);
                }
            }
            __syncthreads();
        }
    }
}

// ---------------------------------------------------------------- per-step fallback (if coop launch fails)
__global__ __launch_bounds__(256) void rnn_step_xp(
    const float* __restrict__ xproj,
    const ushort_t* __restrict__ whhh, const ushort_t* __restrict__ whhl,
    const ushort_t* __restrict__ hph, const ushort_t* __restrict__ hpl,
    ushort_t* __restrict__ hnh, ushort_t* __restrict__ hnl,
    const float* __restrict__ b_hh, float* __restrict__ h32, int t)
{
    __shared__ float red[4][32][34];
    const int tid = threadIdx.x;
    const int wv = tid >> 6, lane = tid & 63;
    const int row16 = lane & 15, kblk = lane >> 4;
    const int lid = blockIdx.x;
    const int rb = lid & 7, cb = lid >> 3;
    const int r0 = rb * 32, c0 = cb * 32;

    const size_t ha0 = (size_t)(r0 + row16) * HH + wv * 256 + kblk * 8;
    const size_t ha1 = (size_t)(r0 + 16 + row16) * HH + wv * 256 + kblk * 8;
    const size_t wb0 = (size_t)(c0 + row16) * HH + wv * 256 + kblk * 8;
    const size_t wb1 = (size_t)(c0 + 16 + row16) * HH + wv * 256 + kblk * 8;

    f32x4 acc[2][2] = {};
    #pragma unroll
    for (int kb = 0; kb < 8; ++kb) {
        const int k = kb * 32;
        short8 ah0 = *(const short8*)(hph + ha0 + k);
        short8 ah1 = *(const short8*)(hph + ha1 + k);
        short8 al0 = *(const short8*)(hpl + ha0 + k);
        short8 al1 = *(const short8*)(hpl + ha1 + k);
        short8 bh0 = *(const short8*)(whhh + wb0 + k);
        short8 bh1 = *(const short8*)(whhh + wb1 + k);
        short8 bl0 = *(const short8*)(whhl + wb0 + k);
        short8 bl1 = *(const short8*)(whhl + wb1 + k);
        MFMA3R(0, 0, ah0, al0, bh0, bl0)
        MFMA3R(0, 1, ah0, al0, bh1, bl1)
        MFMA3R(1, 0, ah1, al1, bh0, bl0)
        MFMA3R(1, 1, ah1, al1, bh1, bl1)
    }
    #pragma unroll
    for (int m = 0; m < 2; ++m)
        #pragma unroll
        for (int n = 0; n < 2; ++n)
            #pragma unroll
            for (int jj = 0; jj < 4; ++jj)
                red[wv][m * 16 + kblk * 4 + jj][n * 16 + row16] = acc[m][n][jj];
    __syncthreads();
    {
        const int mq = wv >> 1, nq = wv & 1;
        const int lc = nq * 16 + row16;
        const int cg = c0 + lc;
        const float biasv = b_hh[cg];
        #pragma unroll
        for (int jj = 0; jj < 4; ++jj) {
            const int lr = mq * 16 + kblk * 4 + jj;
            float v = red[0][lr][lc] + red[1][lr][lc] + red[2][lr][lc] + red[3][lr][lc]
                      + xproj[((size_t)t * BB + (r0 + lr)) * HH + cg] + biasv;
            v = tanhf(v);
            const size_t o = (size_t)(r0 + lr) * HH + cg;
            hnh[o] = bfbits(v);
            hnl[o] = bfbits(v - bffloat(bfbits(v)));
            if (t == TT - 1) h32[o] = v;
        }
    }
}

// ---------------------------------------------------------------- tiny-ws fp32 fallback (R0 path)
__global__ __launch_bounds__(256) void rnn_step(
    const float* __restrict__ x, const float* __restrict__ W_ih,
    const float* __restrict__ W_hh, const float* __restrict__ b_ih,
    const float* __restrict__ b_hh, const float* __restrict__ h_prev,
    float* __restrict__ h_next, int t)
{
    __shared__ float As[32][33];
    __shared__ float Bs[32][33];
    const int r0 = blockIdx.x * 32;
    const int c0 = blockIdx.y * 32;
    const int tid = threadIdx.x;
    const int tr = tid >> 4;
    const int tc = tid & 15;
    float acc00 = 0.f, acc01 = 0.f, acc10 = 0.f, acc11 = 0.f;
    for (int kb = 0; kb < II; kb += 32) {
        #pragma unroll
        for (int l = 0; l < 4; ++l) {
            int idx = tid + l * 256;
            int r = idx >> 5, k = idx & 31;
            As[r][k] = x[((size_t)(r0 + r) * TT + t) * II + kb + k];
            Bs[r][k] = W_ih[(size_t)(c0 + r) * II + kb + k];
        }
        __syncthreads();
        #pragma unroll 8
        for (int k = 0; k < 32; ++k) {
            float a0 = As[2*tr][k], a1 = As[2*tr+1][k];
            float b0 = Bs[2*tc][k], b1 = Bs[2*tc+1][k];
            acc00 += a0 * b0; acc01 += a0 * b1;
            acc10 += a1 * b0; acc11 += a1 * b1;
        }
        __syncthreads();
    }
    for (int kb = 0; kb < HH; kb += 32) {
        #pragma unroll
        for (int l = 0; l < 4; ++l) {
            int idx = tid + l * 256;
            int r = idx >> 5, k = idx & 31;
            As[r][k] = h_prev[(size_t)(r0 + r) * HH + kb + k];
            Bs[r][k] = W_hh[(size_t)(c0 + r) * HH + kb + k];
        }
        __syncthreads();
        #pragma unroll 8
        for (int k = 0; k < 32; ++k) {
            float a0 = As[2*tr][k], a1 = As[2*tr+1][k];
            float b0 = Bs[2*tc][k], b1 = Bs[2*tc+1][k];
            acc00 += a0 * b0; acc01 += a0 * b1;
            acc10 += a1 * b0; acc11 += a1 * b1;
        }
        __syncthreads();
    }
    const int r = r0 + 2 * tr;
    const int c = c0 + 2 * tc;
    const float bias0 = b_ih[c] + b_hh[c];
    const float bias1 = b_ih[c + 1] + b_hh[c + 1];
    h_next[(size_t)r * HH + c]           = tanhf(acc00 + bias0);
    h_next[(size_t)r * HH + c + 1]       = tanhf(acc01 + bias1);
    h_next[(size_t)(r + 1) * HH + c]     = tanhf(acc10 + bias0);
    h_next[(size_t)(r + 1) * HH + c + 1] = tanhf(acc11 + bias1);
}

// ---------------------------------------------------------------- FC
__global__ __launch_bounds__(256) void fc_kernel(
    const float* __restrict__ h, const float* __restrict__ W_fc,
    const float* __restrict__ b_fc, float* __restrict__ out)
{
    const int b = blockIdx.x;
    const int tid = threadIdx.x;
    float p[OO] = {0.f, 0.f, 0.f, 0.f};
    for (int k = tid; k < HH; k += 256) {
        float hv = h[(size_t)b * HH + k];
        #pragma unroll
        for (int o = 0; o < OO; ++o) p[o] += hv * W_fc[(size_t)o * HH + k];
    }
    #pragma unroll
    for (int off = 32; off > 0; off >>= 1) {
        #pragma unroll
        for (int o = 0; o < OO; ++o) p[o] += __shfl_down(p[o], off, 64);
    }
    __shared__ float red[4][OO];
    const int wave = tid >> 6, lane = tid & 63;
    if (lane == 0) {
        #pragma unroll
        for (int o = 0; o < OO; ++o) red[wave][o] = p[o];
    }
    __syncthreads();
    if (tid < OO) {
        float s = red[0][tid] + red[1][tid] + red[2][tid] + red[3][tid] + b_fc[tid];
        out[b * OO + tid] = s;
    }
}

// ---------------------------------------------------------------- launch
extern "C" void kernel_launch(void* const* d_in, const int* in_sizes, int n_in,
                              void* d_out, int out_size, void* d_ws, size_t ws_size,
                              hipStream_t stream) {
    const float* x    = (const float*)d_in[0];
    const float* W_ih = (const float*)d_in[1];
    const float* W_hh = (const float*)d_in[2];
    const float* b_ih = (const float*)d_in[3];
    const float* b_hh = (const float*)d_in[4];
    const float* W_fc = (const float*)d_in[5];
    const float* b_fc = (const float*)d_in[6];
    float* out = (float*)d_out;

    // ws layout (bytes)
    const size_t SZ_XPROJ = (size_t)TT * BB * HH * 4;   // 224 MB fp32
    const size_t SZ_WIH   = (size_t)HH * II * 2;
    const size_t SZ_WHH   = (size_t)HH * HH * 2;
    const size_t SZ_H     = (size_t)BB * HH * 2;
    const size_t OFF_XPROJ = 0;
    const size_t OFF_WIHH  = OFF_XPROJ + SZ_XPROJ;
    const size_t OFF_WIHL  = OFF_WIHH + SZ_WIH;
    const size_t OFF_WHHH  = OFF_WIHL + SZ_WIH;
    const size_t OFF_WHHL  = OFF_WHHH + SZ_WHH;
    const size_t OFF_HAH   = OFF_WHHL + SZ_WHH;
    const size_t OFF_HAL   = OFF_HAH + SZ_H;
    const size_t OFF_HBH   = OFF_HAL + SZ_H;
    const size_t OFF_HBL   = OFF_HBH + SZ_H;
    const size_t OFF_H32   = OFF_HBL + SZ_H;
    const size_t OFF_FLAGS = OFF_H32 + (size_t)BB * HH * 4;
    const size_t NEED      = OFF_FLAGS + 256 * 64;

    char* ws = (char*)d_ws;

    if (ws_size >= NEED) {
        float*    xproj = (float*)(ws + OFF_XPROJ);
        ushort_t* wihh  = (ushort_t*)(ws + OFF_WIHH);
        ushort_t* wihl  = (ushort_t*)(ws + OFF_WIHL);
        ushort_t* whhh  = (ushort_t*)(ws + OFF_WHHH);
        ushort_t* whhl  = (ushort_t*)(ws + OFF_WHHL);
        ushort_t* hAh   = (ushort_t*)(ws + OFF_HAH);
        ushort_t* hAl   = (ushort_t*)(ws + OFF_HAL);
        ushort_t* hBh   = (ushort_t*)(ws + OFF_HBH);
        ushort_t* hBl   = (ushort_t*)(ws + OFF_HBL);
        float*    h32   = (float*)(ws + OFF_H32);
        unsigned* flags = (unsigned*)(ws + OFF_FLAGS);

        // prep: weight splits, zero h plane A + flags, x-projection GEMM
        split_hi_lo<<<128, 256, 0, stream>>>(W_ih, wihh, wihl, (HH * II) / 4);
        split_hi_lo<<<512, 256, 0, stream>>>(W_hh, whhh, whhl, (HH * HH) / 4);
        zero_kernel<<<(int)((2 * SZ_H / 4 + 255) / 256), 256, 0, stream>>>((float*)(ws + OFF_HAH), (int)(2 * SZ_H / 4));
        zero_kernel<<<16, 256, 0, stream>>>((float*)flags, 4096);
        xproj_gemm<<<dim3((TT * BB) / 32, HH / 32), 64, 0, stream>>>(x, wihh, wihl, b_ih, xproj);

        const float* bhhp = b_hh;
        void* args[] = {
            (void*)&xproj, (void*)&whhh, (void*)&whhl,
            (void*)&hAh, (void*)&hAl, (void*)&hBh, (void*)&hBl,
            (void*)&bhhp, (void*)&h32, (void*)&flags
        };
        hipError_t e = hipLaunchCooperativeKernel((void*)rnn_persist2,
                                                  dim3(256), dim3(256), args, 0, stream);
        if (e != hipSuccess) {
            // fallback: per-step loop (kernel boundaries provide coherence)
            for (int t = 0; t < TT; ++t) {
                const int p = t & 1;
                rnn_step_xp<<<256, 256, 0, stream>>>(
                    xproj, whhh, whhl,
                    (p ? hBh : hAh), (p ? hBl : hAl),
                    (p ? hAh : hBh), (p ? hAl : hBl),
                    b_hh, h32, t);
            }
        }
        fc_kernel<<<BB, 256, 0, stream>>>(h32, W_fc, b_fc, out);
    } else {
        // tiny-ws fp32 fallback
        float* h0 = (float*)d_ws;
        float* h1 = h0 + (size_t)BB * HH;
        zero_kernel<<<(BB * HH) / 256, 256, 0, stream>>>(h0, BB * HH);
        for (int t = 0; t < TT; ++t) {
            const float* hp = (t & 1) ? h1 : h0;
            float*       hn = (t & 1) ? h0 : h1;
            rnn_step<<<dim3(8, 32), 256, 0, stream>>>(x, W_ih, W_hh, b_ih, b_hh, hp, hn, t);
        }
        fc_kernel<<<BB, 256, 0, stream>>>(h0, W_fc, b_fc, out);
    }
}

// Round 7
// 1519.342 us; speedup vs baseline: 8.4248x; 1.3271x over previous
//
#include <hip/hip_runtime.h>
#include <hip/hip_bf16.h>
#include <cstddef>
#include <cstdint>

#define BB 256
#define TT 224
#define II 224
#define HH 1024
#define OO 4

typedef __attribute__((ext_vector_type(8))) short short8;   // 8 bf16 (4 VGPRs)
typedef __attribute__((ext_vector_type(4))) float f32x4;    // MFMA accumulator
typedef unsigned short ushort_t;

// ---------------------------------------------------------------- helpers
__device__ __forceinline__ unsigned short bfbits(float v) {
    __hip_bfloat16 b = __float2bfloat16(v);
    union { __hip_bfloat16 b; unsigned short u; } cv; cv.b = b; return cv.u;
}
__device__ __forceinline__ float bffloat(unsigned short u) {
    union { unsigned short u; __hip_bfloat16 b; } cv; cv.u = u; return __bfloat162float(cv.b);
}

// system-scope (bypass L1+L2, meet at MALL) memory ops
__device__ __forceinline__ void ld128_sys(short8& d, const void* p) {
    asm volatile("global_load_dwordx4 %0, %1, off sc0 sc1" : "=v"(d) : "v"(p) : "memory");
}
__device__ __forceinline__ void st16_sys(void* p, unsigned v) {
    asm volatile("global_store_short %0, %1, off sc0 sc1" :: "v"(p), "v"(v) : "memory");
}
__device__ __forceinline__ void stflag(unsigned* p, unsigned v) {
    asm volatile("global_store_dword %0, %1, off sc0 sc1" :: "v"(p), "v"(v) : "memory");
}
__device__ __forceinline__ unsigned ldflag(const unsigned* p) {
    unsigned v;
    asm volatile("global_load_dword %0, %1, off sc0 sc1\n\ts_waitcnt vmcnt(0)"
                 : "=v"(v) : "v"(p) : "memory");
    return v;
}
__device__ __forceinline__ void wait_vm0() {
    asm volatile("s_waitcnt vmcnt(0)" ::: "memory");
    __builtin_amdgcn_sched_barrier(0);
}
__device__ __forceinline__ void wait_vm8() {
    asm volatile("s_waitcnt vmcnt(8)" ::: "memory");
    __builtin_amdgcn_sched_barrier(0);
}

// fast tanh: (1 - e^-2v)/(1 + e^-2v), clamped; ~1 ulp-class, plenty for bf16 path
__device__ __forceinline__ float fast_tanh(float v) {
    v = fminf(fmaxf(v, -15.f), 15.f);
    const float e = __expf(-2.f * v);
    return (1.f - e) * __builtin_amdgcn_rcpf(1.f + e);
}

#define MFMA3R(m, n, AH, AL, BH, BL)                                                  \
    acc[m][n] = __builtin_amdgcn_mfma_f32_16x16x32_bf16(AH, BH, acc[m][n], 0, 0, 0);  \
    acc[m][n] = __builtin_amdgcn_mfma_f32_16x16x32_bf16(AH, BL, acc[m][n], 0, 0, 0);  \
    acc[m][n] = __builtin_amdgcn_mfma_f32_16x16x32_bf16(AL, BH, acc[m][n], 0, 0, 0);

// ---------------------------------------------------------------- utility kernels
__global__ void zero_kernel(float* __restrict__ p, int n) {
    int i = blockIdx.x * blockDim.x + threadIdx.x;
    if (i < n) p[i] = 0.f;
}

__global__ __launch_bounds__(256) void split_hi_lo(
    const float* __restrict__ src, ushort_t* __restrict__ hi,
    ushort_t* __restrict__ lo, int n4)
{
    struct u4 { ushort_t v[4]; };
    const int stride = gridDim.x * blockDim.x;
    for (int i = blockIdx.x * blockDim.x + threadIdx.x; i < n4; i += stride) {
        float4 s = ((const float4*)src)[i];
        float vv[4] = {s.x, s.y, s.z, s.w};
        u4 h, l;
        #pragma unroll
        for (int j = 0; j < 4; ++j) {
            unsigned short hb = bfbits(vv[j]);
            h.v[j] = hb;
            l.v[j] = bfbits(vv[j] - bffloat(hb));
        }
        ((u4*)hi)[i] = h;
        ((u4*)lo)[i] = l;
    }
}

// ---------------------------------------------------------------- x-projection GEMM
// xproj[m][c], m = t*256 + b : xproj = x W_ih^T + b_ih (hi/lo split precision)
__global__ __launch_bounds__(64) void xproj_gemm(
    const float* __restrict__ x, const ushort_t* __restrict__ wihh,
    const ushort_t* __restrict__ wihl, const float* __restrict__ b_ih,
    float* __restrict__ xproj)
{
    const int lane = threadIdx.x;
    const int row16 = lane & 15;
    const int kblk = lane >> 4;
    const int m0 = blockIdx.x * 32;
    const int c0 = blockIdx.y * 32;
    const int tt = m0 >> 8;
    const int brow = m0 & 255;

    f32x4 acc[2][2] = {};
    const size_t xa0 = ((size_t)(brow + row16) * TT + tt) * II;
    const size_t xa1 = ((size_t)(brow + 16 + row16) * TT + tt) * II;
    const size_t wb0 = (size_t)(c0 + row16) * II;
    const size_t wb1 = (size_t)(c0 + 16 + row16) * II;

    #pragma unroll
    for (int kb = 0; kb < 7; ++kb) {
        const int k = kb * 32 + kblk * 8;
        short8 ah0, al0, ah1, al1;
        {
            const float* p = x + xa0 + k;
            #pragma unroll
            for (int j2 = 0; j2 < 8; ++j2) {
                float v = p[j2];
                unsigned short hb = bfbits(v);
                ah0[j2] = (short)hb;
                al0[j2] = (short)bfbits(v - bffloat(hb));
            }
            p = x + xa1 + k;
            #pragma unroll
            for (int j2 = 0; j2 < 8; ++j2) {
                float v = p[j2];
                unsigned short hb = bfbits(v);
                ah1[j2] = (short)hb;
                al1[j2] = (short)bfbits(v - bffloat(hb));
            }
        }
        short8 bh0 = *(const short8*)(wihh + wb0 + k);
        short8 bh1 = *(const short8*)(wihh + wb1 + k);
        short8 bl0 = *(const short8*)(wihl + wb0 + k);
        short8 bl1 = *(const short8*)(wihl + wb1 + k);
        MFMA3R(0, 0, ah0, al0, bh0, bl0)
        MFMA3R(0, 1, ah0, al0, bh1, bl1)
        MFMA3R(1, 0, ah1, al1, bh0, bl0)
        MFMA3R(1, 1, ah1, al1, bh1, bl1)
    }
    #pragma unroll
    for (int n = 0; n < 2; ++n) {
        const int c = c0 + n * 16 + row16;
        const float bi = b_ih[c];
        #pragma unroll
        for (int m = 0; m < 2; ++m)
            #pragma unroll
            for (int jj = 0; jj < 4; ++jj) {
                const int mr = m0 + m * 16 + kblk * 4 + jj;
                xproj[(size_t)mr * HH + c] = acc[m][n][jj] + bi;
            }
    }
}

// ---------------------------------------------------------------- persistent RNN (R7)
// 256 WGs (cooperative, 1/CU) x 256 thr. 16 row-groups (16 rows each) x 16
// col-blocks (64 cols each). W_hh slice lives ENTIRELY in VGPRs (hi+lo = 256
// VGPR/wave; waves K-split 4 x 256). h exchange group-local through the MALL
// (sc0 sc1) -> no fences, no L2 disturbance. LDS only for the 16.5 KB cross-
// wave K-reduction. Per-group 16-flag barrier; ping-pong distance-1 safe.
__global__ __launch_bounds__(256, 1) void rnn_persist3(
    const float* __restrict__ xproj,
    const ushort_t* __restrict__ whhh, const ushort_t* __restrict__ whhl,
    ushort_t* hAh, ushort_t* hAl, ushort_t* hBh, ushort_t* hBl,
    const float* __restrict__ b_hh, float* __restrict__ h32,
    unsigned* __restrict__ flags)
{
    __shared__ float red[4][16][66];   // stride 66: 2 lanes/bank = free

    const int tid = threadIdx.x;
    const int wv = tid >> 6, lane = tid & 63;
    const int row16 = lane & 15, kblk = lane >> 4;
    const int lid = blockIdx.x;
    const int rb = lid & 15;           // row-group: rows 16*rb..+15
    const int cb = lid >> 4;           // col-block: cols 64*cb..+63
    const int r0 = rb * 16, c0 = cb * 64;

    // ---- W_hh slice -> registers (once): [kb][n], hi and lo planes ----
    short8 wH[8][4], wL[8][4];
    #pragma unroll
    for (int kb = 0; kb < 8; ++kb)
        #pragma unroll
        for (int n = 0; n < 4; ++n) {
            const size_t wb = (size_t)(c0 + n * 16 + row16) * HH + wv * 256 + kb * 32 + kblk * 8;
            wH[kb][n] = *(const short8*)(whhh + wb);
            wL[kb][n] = *(const short8*)(whhl + wb);
        }

    // epilogue constants: thread owns 4 rows x 1 col of the 16x64 tile
    const int ecol = tid & 63;
    const int erow0 = (tid >> 6) * 4;
    const int cg = c0 + ecol;
    const float biasv = b_hh[cg];

    const size_t ha = (size_t)(r0 + row16) * HH + wv * 256 + kblk * 8;

    for (int t = 0; t < TT; ++t) {
        const ushort_t* hph = (t & 1) ? hBh : hAh;
        const ushort_t* hpl = (t & 1) ? hBl : hAl;
        ushort_t* hnh = (t & 1) ? hAh : hBh;
        ushort_t* hnl = (t & 1) ? hAl : hBl;

        // xproj for epilogue (plain loads; streamed once, consumed late)
        float xp[4];
        #pragma unroll
        for (int jj = 0; jj < 4; ++jj)
            xp[jj] = xproj[((size_t)t * BB + (r0 + erow0 + jj)) * HH + cg];

        // h prefetch: 16 sys-scope loads in kb order (first 8 = kb0..3)
        short8 fh[8], fl[8];
        #pragma unroll
        for (int kb = 0; kb < 8; ++kb) {
            ld128_sys(fh[kb], hph + ha + kb * 32);
            ld128_sys(fl[kb], hpl + ha + kb * 32);
        }

        f32x4 acc[4] = {};
        wait_vm8();     // kb0..3 ready (counted: >=8 of our h-loads completed)
        #pragma unroll
        for (int kb = 0; kb < 4; ++kb)
            #pragma unroll
            for (int n = 0; n < 4; ++n) {
                acc[n] = __builtin_amdgcn_mfma_f32_16x16x32_bf16(fh[kb], wH[kb][n], acc[n], 0, 0, 0);
                acc[n] = __builtin_amdgcn_mfma_f32_16x16x32_bf16(fh[kb], wL[kb][n], acc[n], 0, 0, 0);
                acc[n] = __builtin_amdgcn_mfma_f32_16x16x32_bf16(fl[kb], wH[kb][n], acc[n], 0, 0, 0);
            }
        wait_vm0();     // kb4..7 (+xproj) ready
        #pragma unroll
        for (int kb = 4; kb < 8; ++kb)
            #pragma unroll
            for (int n = 0; n < 4; ++n) {
                acc[n] = __builtin_amdgcn_mfma_f32_16x16x32_bf16(fh[kb], wH[kb][n], acc[n], 0, 0, 0);
                acc[n] = __builtin_amdgcn_mfma_f32_16x16x32_bf16(fh[kb], wL[kb][n], acc[n], 0, 0, 0);
                acc[n] = __builtin_amdgcn_mfma_f32_16x16x32_bf16(fl[kb], wH[kb][n], acc[n], 0, 0, 0);
            }

        // cross-wave K reduction through LDS
        #pragma unroll
        for (int n = 0; n < 4; ++n)
            #pragma unroll
            for (int jj = 0; jj < 4; ++jj)
                red[wv][kblk * 4 + jj][n * 16 + row16] = acc[n][jj];
        __syncthreads();

        // epilogue: bias + xproj + tanh, write hi/lo bf16 (sys scope)
        #pragma unroll
        for (int jj = 0; jj < 4; ++jj) {
            const int lr = erow0 + jj;
            float v = red[0][lr][ecol] + red[1][lr][ecol] + red[2][lr][ecol] + red[3][lr][ecol]
                      + xp[jj] + biasv;
            v = fast_tanh(v);
            const size_t o = (size_t)(r0 + lr) * HH + cg;
            const unsigned short hb = bfbits(v);
            st16_sys(hnh + o, (unsigned)hb);
            st16_sys(hnl + o, (unsigned)bfbits(v - bffloat(hb)));
            if (t == TT - 1) h32[o] = v;
        }

        wait_vm0();            // h stores acked at MALL
        __syncthreads();       // all waves' stores done (also fences red reuse)

        if (t != TT - 1) {
            if (tid == 0) stflag(flags + (size_t)lid * 16, (unsigned)(t + 1));
            if (tid < 64) {    // wave 0 polls the group's 16 flags
                const unsigned want = (unsigned)(t + 1);
                const unsigned* fp = flags + (size_t)(rb + 16 * (tid & 15)) * 16;
                while (true) {
                    unsigned vf = ldflag(fp);
                    if (__ballot(vf >= want) == ~0ull) break;
                    __builtin_amdgcn_s_sleep(1);
                }
            }
            __syncthreads();
        }
    }
}

// ---------------------------------------------------------------- per-step fallback (if coop launch fails)
__global__ __launch_bounds__(256) void rnn_step_xp(
    const float* __restrict__ xproj,
    const ushort_t* __restrict__ whhh, const ushort_t* __restrict__ whhl,
    const ushort_t* __restrict__ hph, const ushort_t* __restrict__ hpl,
    ushort_t* __restrict__ hnh, ushort_t* __restrict__ hnl,
    const float* __restrict__ b_hh, float* __restrict__ h32, int t)
{
    __shared__ float red[4][32][34];
    const int tid = threadIdx.x;
    const int wv = tid >> 6, lane = tid & 63;
    const int row16 = lane & 15, kblk = lane >> 4;
    const int lid = blockIdx.x;
    const int rb = lid & 7, cb = lid >> 3;
    const int r0 = rb * 32, c0 = cb * 32;

    const size_t ha0 = (size_t)(r0 + row16) * HH + wv * 256 + kblk * 8;
    const size_t ha1 = (size_t)(r0 + 16 + row16) * HH + wv * 256 + kblk * 8;
    const size_t wb0 = (size_t)(c0 + row16) * HH + wv * 256 + kblk * 8;
    const size_t wb1 = (size_t)(c0 + 16 + row16) * HH + wv * 256 + kblk * 8;

    f32x4 acc[2][2] = {};
    #pragma unroll
    for (int kb = 0; kb < 8; ++kb) {
        const int k = kb * 32;
        short8 ah0 = *(const short8*)(hph + ha0 + k);
        short8 ah1 = *(const short8*)(hph + ha1 + k);
        short8 al0 = *(const short8*)(hpl + ha0 + k);
        short8 al1 = *(const short8*)(hpl + ha1 + k);
        short8 bh0 = *(const short8*)(whhh + wb0 + k);
        short8 bh1 = *(const short8*)(whhh + wb1 + k);
        short8 bl0 = *(const short8*)(whhl + wb0 + k);
        short8 bl1 = *(const short8*)(whhl + wb1 + k);
        MFMA3R(0, 0, ah0, al0, bh0, bl0)
        MFMA3R(0, 1, ah0, al0, bh1, bl1)
        MFMA3R(1, 0, ah1, al1, bh0, bl0)
        MFMA3R(1, 1, ah1, al1, bh1, bl1)
    }
    #pragma unroll
    for (int m = 0; m < 2; ++m)
        #pragma unroll
        for (int n = 0; n < 2; ++n)
            #pragma unroll
            for (int jj = 0; jj < 4; ++jj)
                red[wv][m * 16 + kblk * 4 + jj][n * 16 + row16] = acc[m][n][jj];
    __syncthreads();
    {
        const int mq = wv >> 1, nq = wv & 1;
        const int lc = nq * 16 + row16;
        const int cg = c0 + lc;
        const float biasv = b_hh[cg];
        #pragma unroll
        for (int jj = 0; jj < 4; ++jj) {
            const int lr = mq * 16 + kblk * 4 + jj;
            float v = red[0][lr][lc] + red[1][lr][lc] + red[2][lr][lc] + red[3][lr][lc]
                      + xproj[((size_t)t * BB + (r0 + lr)) * HH + cg] + biasv;
            v = tanhf(v);
            const size_t o = (size_t)(r0 + lr) * HH + cg;
            const unsigned short hb = bfbits(v);
            hnh[o] = hb;
            hnl[o] = bfbits(v - bffloat(hb));
            if (t == TT - 1) h32[o] = v;
        }
    }
}

// ---------------------------------------------------------------- tiny-ws fp32 fallback (R0 path)
__global__ __launch_bounds__(256) void rnn_step(
    const float* __restrict__ x, const float* __restrict__ W_ih,
    const float* __restrict__ W_hh, const float* __restrict__ b_ih,
    const float* __restrict__ b_hh, const float* __restrict__ h_prev,
    float* __restrict__ h_next, int t)
{
    __shared__ float As[32][33];
    __shared__ float Bs[32][33];
    const int r0 = blockIdx.x * 32;
    const int c0 = blockIdx.y * 32;
    const int tid = threadIdx.x;
    const int tr = tid >> 4;
    const int tc = tid & 15;
    float acc00 = 0.f, acc01 = 0.f, acc10 = 0.f, acc11 = 0.f;
    for (int kb = 0; kb < II; kb += 32) {
        #pragma unroll
        for (int l = 0; l < 4; ++l) {
            int idx = tid + l * 256;
            int r = idx >> 5, k = idx & 31;
            As[r][k] = x[((size_t)(r0 + r) * TT + t) * II + kb + k];
            Bs[r][k] = W_ih[(size_t)(c0 + r) * II + kb + k];
        }
        __syncthreads();
        #pragma unroll 8
        for (int k = 0; k < 32; ++k) {
            float a0 = As[2*tr][k], a1 = As[2*tr+1][k];
            float b0 = Bs[2*tc][k], b1 = Bs[2*tc+1][k];
            acc00 += a0 * b0; acc01 += a0 * b1;
            acc10 += a1 * b0; acc11 += a1 * b1;
        }
        __syncthreads();
    }
    for (int kb = 0; kb < HH; kb += 32) {
        #pragma unroll
        for (int l = 0; l < 4; ++l) {
            int idx = tid + l * 256;
            int r = idx >> 5, k = idx & 31;
            As[r][k] = h_prev[(size_t)(r0 + r) * HH + kb + k];
            Bs[r][k] = W_hh[(size_t)(c0 + r) * HH + kb + k];
        }
        __syncthreads();
        #pragma unroll 8
        for (int k = 0; k < 32; ++k) {
            float a0 = As[2*tr][k], a1 = As[2*tr+1][k];
            float b0 = Bs[2*tc][k], b1 = Bs[2*tc+1][k];
            acc00 += a0 * b0; acc01 += a0 * b1;
            acc10 += a1 * b0; acc11 += a1 * b1;
        }
        __syncthreads();
    }
    const int r = r0 + 2 * tr;
    const int c = c0 + 2 * tc;
    const float bias0 = b_ih[c] + b_hh[c];
    const float bias1 = b_ih[c + 1] + b_hh[c + 1];
    h_next[(size_t)r * HH + c]           = tanhf(acc00 + bias0);
    h_next[(size_t)r * HH + c + 1]       = tanhf(acc01 + bias1);
    h_next[(size_t)(r + 1) * HH + c]     = tanhf(acc10 + bias0);
    h_next[(size_t)(r + 1) * HH + c + 1] = tanhf(acc11 + bias1);
}

// ---------------------------------------------------------------- FC
__global__ __launch_bounds__(256) void fc_kernel(
    const float* __restrict__ h, const float* __restrict__ W_fc,
    const float* __restrict__ b_fc, float* __restrict__ out)
{
    const int b = blockIdx.x;
    const int tid = threadIdx.x;
    float p[OO] = {0.f, 0.f, 0.f, 0.f};
    for (int k = tid; k < HH; k += 256) {
        float hv = h[(size_t)b * HH + k];
        #pragma unroll
        for (int o = 0; o < OO; ++o) p[o] += hv * W_fc[(size_t)o * HH + k];
    }
    #pragma unroll
    for (int off = 32; off > 0; off >>= 1) {
        #pragma unroll
        for (int o = 0; o < OO; ++o) p[o] += __shfl_down(p[o], off, 64);
    }
    __shared__ float red[4][OO];
    const int wave = tid >> 6, lane = tid & 63;
    if (lane == 0) {
        #pragma unroll
        for (int o = 0; o < OO; ++o) red[wave][o] = p[o];
    }
    __syncthreads();
    if (tid < OO) {
        float s = red[0][tid] + red[1][tid] + red[2][tid] + red[3][tid] + b_fc[tid];
        out[b * OO + tid] = s;
    }
}

// ---------------------------------------------------------------- launch
extern "C" void kernel_launch(void* const* d_in, const int* in_sizes, int n_in,
                              void* d_out, int out_size, void* d_ws, size_t ws_size,
                              hipStream_t stream) {
    const float* x    = (const float*)d_in[0];
    const float* W_ih = (const float*)d_in[1];
    const float* W_hh = (const float*)d_in[2];
    const float* b_ih = (const float*)d_in[3];
    const float* b_hh = (const float*)d_in[4];
    const float* W_fc = (const float*)d_in[5];
    const float* b_fc = (const float*)d_in[6];
    float* out = (float*)d_out;

    // ws layout (bytes)
    const size_t SZ_XPROJ = (size_t)TT * BB * HH * 4;   // 224 MB fp32
    const size_t SZ_WIH   = (size_t)HH * II * 2;
    const size_t SZ_WHH   = (size_t)HH * HH * 2;
    const size_t SZ_H     = (size_t)BB * HH * 2;
    const size_t OFF_XPROJ = 0;
    const size_t OFF_WIHH  = OFF_XPROJ + SZ_XPROJ;
    const size_t OFF_WIHL  = OFF_WIHH + SZ_WIH;
    const size_t OFF_WHHH  = OFF_WIHL + SZ_WIH;
    const size_t OFF_WHHL  = OFF_WHHH + SZ_WHH;
    const size_t OFF_HAH   = OFF_WHHL + SZ_WHH;
    const size_t OFF_HAL   = OFF_HAH + SZ_H;
    const size_t OFF_HBH   = OFF_HAL + SZ_H;
    const size_t OFF_HBL   = OFF_HBH + SZ_H;
    const size_t OFF_H32   = OFF_HBL + SZ_H;
    const size_t OFF_FLAGS = OFF_H32 + (size_t)BB * HH * 4;
    const size_t NEED      = OFF_FLAGS + 256 * 64;

    char* ws = (char*)d_ws;

    if (ws_size >= NEED) {
        float*    xproj = (float*)(ws + OFF_XPROJ);
        ushort_t* wihh  = (ushort_t*)(ws + OFF_WIHH);
        ushort_t* wihl  = (ushort_t*)(ws + OFF_WIHL);
        ushort_t* whhh  = (ushort_t*)(ws + OFF_WHHH);
        ushort_t* whhl  = (ushort_t*)(ws + OFF_WHHL);
        ushort_t* hAh   = (ushort_t*)(ws + OFF_HAH);
        ushort_t* hAl   = (ushort_t*)(ws + OFF_HAL);
        ushort_t* hBh   = (ushort_t*)(ws + OFF_HBH);
        ushort_t* hBl   = (ushort_t*)(ws + OFF_HBL);
        float*    h32   = (float*)(ws + OFF_H32);
        unsigned* flags = (unsigned*)(ws + OFF_FLAGS);

        // prep: weight splits, zero h plane A + flags, x-projection GEMM
        split_hi_lo<<<128, 256, 0, stream>>>(W_ih, wihh, wihl, (HH * II) / 4);
        split_hi_lo<<<512, 256, 0, stream>>>(W_hh, whhh, whhl, (HH * HH) / 4);
        zero_kernel<<<(int)((2 * SZ_H / 4 + 255) / 256), 256, 0, stream>>>((float*)(ws + OFF_HAH), (int)(2 * SZ_H / 4));
        zero_kernel<<<16, 256, 0, stream>>>((float*)flags, 4096);
        xproj_gemm<<<dim3((TT * BB) / 32, HH / 32), 64, 0, stream>>>(x, wihh, wihl, b_ih, xproj);

        const float* bhhp = b_hh;
        void* args[] = {
            (void*)&xproj, (void*)&whhh, (void*)&whhl,
            (void*)&hAh, (void*)&hAl, (void*)&hBh, (void*)&hBl,
            (void*)&bhhp, (void*)&h32, (void*)&flags
        };
        hipError_t e = hipLaunchCooperativeKernel((void*)rnn_persist3,
                                                  dim3(256), dim3(256), args, 0, stream);
        if (e != hipSuccess) {
            // fallback: per-step loop (kernel boundaries provide coherence)
            for (int t = 0; t < TT; ++t) {
                const int p = t & 1;
                rnn_step_xp<<<256, 256, 0, stream>>>(
                    xproj, whhh, whhl,
                    (p ? hBh : hAh), (p ? hBl : hAl),
                    (p ? hAh : hBh), (p ? hAl : hBl),
                    b_hh, h32, t);
            }
        }
        fc_kernel<<<BB, 256, 0, stream>>>(h32, W_fc, b_fc, out);
    } else {
        // tiny-ws fp32 fallback
        float* h0 = (float*)d_ws;
        float* h1 = h0 + (size_t)BB * HH;
        zero_kernel<<<(BB * HH) / 256, 256, 0, stream>>>(h0, BB * HH);
        for (int t = 0; t < TT; ++t) {
            const float* hp = (t & 1) ? h1 : h0;
            float*       hn = (t & 1) ? h0 : h1;
            rnn_step<<<dim3(8, 32), 256, 0, stream>>>(x, W_ih, W_hh, b_ih, b_hh, hp, hn, t);
        }
        fc_kernel<<<BB, 256, 0, stream>>>(h0, W_fc, b_fc, out);
    }
}

// Round 9
// 1141.774 us; speedup vs baseline: 11.2107x; 1.3307x over previous
//
#include <hip/hip_runtime.h>
#include <hip/hip_bf16.h>
#include <cstddef>

#define BB 256
#define TT 224
#define II 224
#define HH 1024
#define OO 4

typedef __attribute__((ext_vector_type(8))) short short8;   // 8 bf16 (4 VGPRs)
typedef __attribute__((ext_vector_type(4))) float f32x4;    // MFMA accumulator
typedef unsigned short ushort_t;

// ---------------------------------------------------------------- helpers
__device__ __forceinline__ unsigned short bfbits(float v) {
    __hip_bfloat16 b = __float2bfloat16(v);
    union { __hip_bfloat16 b; unsigned short u; } cv; cv.b = b; return cv.u;
}
__device__ __forceinline__ float bffloat(unsigned short u) {
    union { unsigned short u; __hip_bfloat16 b; } cv; cv.u = u; return __bfloat162float(cv.b);
}

// asm VMEM ops: ALL hot-loop VMEM is asm so counted vmcnt windows are exact.
// NOTE gfx950 syntax: offset: immediate must PRECEDE sc0/sc1 cache flags.
#define LD128(d, p)              asm volatile("global_load_dwordx4 %0, %1, off" : "=v"(d) : "v"(p) : "memory")
#define LD128_OFF(d, p, off)     asm volatile("global_load_dwordx4 %0, %1, off offset:" #off : "=v"(d) : "v"(p) : "memory")
#define LD128_SYS_OFF(d, p, off) asm volatile("global_load_dwordx4 %0, %1, off offset:" #off " sc0 sc1" : "=v"(d) : "v"(p) : "memory")
#define ST16_SYS_OFF(p, v, off)  asm volatile("global_store_short %0, %1, off offset:" #off " sc0 sc1" :: "v"(p), "v"(v) : "memory")
#define WAIT_VM(n) do { asm volatile("s_waitcnt vmcnt(" #n ")" ::: "memory"); __builtin_amdgcn_sched_barrier(0); } while (0)

__device__ __forceinline__ void stflag(unsigned* p, unsigned v) {
    asm volatile("global_store_dword %0, %1, off sc0 sc1" :: "v"(p), "v"(v) : "memory");
}
__device__ __forceinline__ unsigned ldflag(const unsigned* p) {
    unsigned v;
    asm volatile("global_load_dword %0, %1, off sc0 sc1\n\ts_waitcnt vmcnt(0)"
                 : "=v"(v) : "v"(p) : "memory");
    return v;
}

// fast tanh: (1 - e^-2v)/(1 + e^-2v), clamped
__device__ __forceinline__ float fast_tanh(float v) {
    v = fminf(fmaxf(v, -15.f), 15.f);
    const float e = __expf(-2.f * v);
    return (1.f - e) * __builtin_amdgcn_rcpf(1.f + e);
}

#define MFMA(a, b, c) __builtin_amdgcn_mfma_f32_16x16x32_bf16(a, b, c, 0, 0, 0)

// ---------------------------------------------------------------- utility kernels
__global__ void zero_kernel(float* __restrict__ p, int n) {
    int i = blockIdx.x * blockDim.x + threadIdx.x;
    if (i < n) p[i] = 0.f;
}

__global__ __launch_bounds__(256) void split_hi_lo(
    const float* __restrict__ src, ushort_t* __restrict__ hi,
    ushort_t* __restrict__ lo, int n4)
{
    struct u4 { ushort_t v[4]; };
    const int stride = gridDim.x * blockDim.x;
    for (int i = blockIdx.x * blockDim.x + threadIdx.x; i < n4; i += stride) {
        float4 s = ((const float4*)src)[i];
        float vv[4] = {s.x, s.y, s.z, s.w};
        u4 h, l;
        #pragma unroll
        for (int j = 0; j < 4; ++j) {
            unsigned short hb = bfbits(vv[j]);
            h.v[j] = hb;
            l.v[j] = bfbits(vv[j] - bffloat(hb));
        }
        ((u4*)hi)[i] = h;
        ((u4*)lo)[i] = l;
    }
}

// ---------------------------------------------------------------- persistent RNN (R9 = R8 w/ asm fix)
// 256 WGs (cooperative, 1/CU) x 512 thr (8 waves). 16 row-groups (16 rows) x
// 16 col-blocks (64 cols). Wave wv K-splits H into 128-slices; W_hh slice
// (128 K x 64 cols x hi/lo = 128 VGPR) asm-staged into registers ONCE.
// x-projection folded in-step from pre-split bf16 planes (wave wv owns I-kb wv,
// wave 7 none). h exchange group-local via MALL (sc0 sc1). Per-wave 2-producer
// flag polls; the block's 8 waves collectively cover all 16 group flags before
// any epilogue store (WAR-safe). All loop VMEM is inline asm (exact vmcnt).
__global__ __launch_bounds__(512, 2) void rnn_persist4(
    const ushort_t* __restrict__ xh,   const ushort_t* __restrict__ xl,
    const ushort_t* __restrict__ wihh, const ushort_t* __restrict__ wihl,
    const ushort_t* __restrict__ whhh, const ushort_t* __restrict__ whhl,
    ushort_t* hAh, ushort_t* hAl, ushort_t* hBh, ushort_t* hBl,
    const float* __restrict__ b_ih, const float* __restrict__ b_hh,
    float* __restrict__ h32, unsigned* __restrict__ flags)
{
    __shared__ float red[8][16][66];   // 33.8 KB; write/read both 2 lanes/bank

    const int tid = threadIdx.x;
    const int wv = tid >> 6, lane = tid & 63;
    const int row16 = lane & 15, kblk = lane >> 4;
    const int lid = blockIdx.x;
    const int rb = lid & 15;           // row-group: rows 16*rb..+15
    const int cb = lid >> 4;           // col-block: cols 64*cb..+63
    const int r0 = rb * 16, c0 = cb * 64;

    // ---- stage W_hh K-slice into registers via asm loads (once) ----
    short8 wh[4][4], wl[4][4];         // [n][kb]
    #pragma unroll
    for (int n = 0; n < 4; ++n) {
        const ushort_t* bh = whhh + (size_t)(c0 + n * 16 + row16) * HH + 128 * wv + kblk * 8;
        const ushort_t* bl = whhl + (size_t)(c0 + n * 16 + row16) * HH + 128 * wv + kblk * 8;
        LD128_OFF(wh[n][0], bh, 0);   LD128_OFF(wh[n][1], bh, 64);
        LD128_OFF(wh[n][2], bh, 128); LD128_OFF(wh[n][3], bh, 192);
        LD128_OFF(wl[n][0], bl, 0);   LD128_OFF(wl[n][1], bl, 64);
        LD128_OFF(wl[n][2], bl, 128); LD128_OFF(wl[n][3], bl, 192);
    }
    WAIT_VM(0);

    // epilogue mapping: thread = (col lane, rows wv*2 + {0,1})
    const int cgl = c0 + lane;
    const int erow0 = wv * 2;
    const float biasv = b_ih[cgl] + b_hh[cgl];

    const size_t ha = (size_t)(r0 + row16) * HH + 128 * wv + kblk * 8;
    const size_t xrow = (size_t)(r0 + row16) * TT;
    const size_t xcol = (size_t)wv * 32 + kblk * 8;

    const int jprod = 2 * wv + (lane & 1);   // wave's 2 producers (32 lanes each)
    const unsigned* myflag = flags + ((size_t)jprod * 16 + rb) * 16;
    unsigned* ourflag = flags + (size_t)lid * 16;

    for (int t = 0; t < TT; ++t) {
        const ushort_t* hph = (t & 1) ? hBh : hAh;
        const ushort_t* hpl = (t & 1) ? hBl : hAl;
        ushort_t* hnh = (t & 1) ? hAh : hBh;
        ushort_t* hnl = (t & 1) ? hAl : hBl;

        // ---- per-wave poll: producers of our K-chunks set flag = t after step t-1
        if (t) {
            while (true) {
                unsigned vf = ldflag(myflag);
                if (__ballot(vf >= (unsigned)t) == ~0ull) break;
                __builtin_amdgcn_s_sleep(1);
            }
        }

        // ---- issue x + W_ih loads (waves 0..6), then h loads (all waves)
        short8 fxh{}, fxl{}, wih_[4], wil_[4];
        if (wv < 7) {
            const ushort_t* px = xh + (xrow + t) * II + xcol;
            const ushort_t* ql = xl + (xrow + t) * II + xcol;
            LD128(fxh, px);
            LD128(fxl, ql);
            #pragma unroll
            for (int n = 0; n < 4; ++n) {
                LD128(wih_[n], wihh + (size_t)(c0 + n * 16 + row16) * II + xcol);
                LD128(wil_[n], wihl + (size_t)(c0 + n * 16 + row16) * II + xcol);
            }
        }
        short8 fh[4], fl[4];
        {
            const ushort_t* ph = hph + ha;
            const ushort_t* pl = hpl + ha;
            LD128_SYS_OFF(fh[0], ph, 0);   LD128_SYS_OFF(fl[0], pl, 0);
            LD128_SYS_OFF(fh[1], ph, 64);  LD128_SYS_OFF(fl[1], pl, 64);
            LD128_SYS_OFF(fh[2], ph, 128); LD128_SYS_OFF(fl[2], pl, 128);
            LD128_SYS_OFF(fh[3], ph, 192); LD128_SYS_OFF(fl[3], pl, 192);
        }

        f32x4 acc[4] = {};
        // ---- x-projection MFMAs overlap the h sys-load latency
        if (wv < 7) {
            WAIT_VM(8);    // fx(2)+wi(8) complete; 8 h loads outstanding
            #pragma unroll
            for (int n = 0; n < 4; ++n) {
                acc[n] = MFMA(fxh, wih_[n], acc[n]);
                acc[n] = MFMA(fxh, wil_[n], acc[n]);
                acc[n] = MFMA(fxl, wih_[n], acc[n]);
            }
        }
        WAIT_VM(4);        // fh/fl kb0,kb1 ready
        #pragma unroll
        for (int kb = 0; kb < 2; ++kb)
            #pragma unroll
            for (int n = 0; n < 4; ++n) {
                acc[n] = MFMA(fh[kb], wh[n][kb], acc[n]);
                acc[n] = MFMA(fh[kb], wl[n][kb], acc[n]);
                acc[n] = MFMA(fl[kb], wh[n][kb], acc[n]);
            }
        WAIT_VM(0);        // kb2,kb3 ready
        #pragma unroll
        for (int kb = 2; kb < 4; ++kb)
            #pragma unroll
            for (int n = 0; n < 4; ++n) {
                acc[n] = MFMA(fh[kb], wh[n][kb], acc[n]);
                acc[n] = MFMA(fh[kb], wl[n][kb], acc[n]);
                acc[n] = MFMA(fl[kb], wh[n][kb], acc[n]);
            }

        // ---- cross-wave K reduction
        #pragma unroll
        for (int n = 0; n < 4; ++n)
            #pragma unroll
            for (int jj = 0; jj < 4; ++jj)
                red[wv][kblk * 4 + jj][n * 16 + row16] = acc[n][jj];
        __syncthreads();

        // ---- epilogue: 2 rows x 1 col per thread
        float v0 = biasv, v1 = biasv;
        #pragma unroll
        for (int w = 0; w < 8; ++w) {
            v0 += red[w][erow0][lane];
            v1 += red[w][erow0 + 1][lane];
        }
        v0 = fast_tanh(v0);
        v1 = fast_tanh(v1);
        const size_t o = (size_t)(r0 + erow0) * HH + cgl;
        const unsigned short b0 = bfbits(v0), b1 = bfbits(v1);
        ST16_SYS_OFF(hnh + o, (unsigned)b0, 0);
        ST16_SYS_OFF(hnh + o, (unsigned)b1, 2048);
        ST16_SYS_OFF(hnl + o, (unsigned)bfbits(v0 - bffloat(b0)), 0);
        ST16_SYS_OFF(hnl + o, (unsigned)bfbits(v1 - bffloat(b1)), 2048);
        if (t == TT - 1) { h32[o] = v0; h32[o + HH] = v1; }

        WAIT_VM(0);        // stores acked at MALL
        __syncthreads();   // all waves stored; also protects red reuse
        if (tid == 0) stflag(ourflag, (unsigned)(t + 1));
    }
}

// ---------------------------------------------------------------- per-step fallback (coop launch fail)
__global__ __launch_bounds__(512) void rnn_step_f(
    const ushort_t* __restrict__ xh,   const ushort_t* __restrict__ xl,
    const ushort_t* __restrict__ wihh, const ushort_t* __restrict__ wihl,
    const ushort_t* __restrict__ whhh, const ushort_t* __restrict__ whhl,
    const ushort_t* __restrict__ hph,  const ushort_t* __restrict__ hpl,
    ushort_t* __restrict__ hnh, ushort_t* __restrict__ hnl,
    const float* __restrict__ b_ih, const float* __restrict__ b_hh,
    float* __restrict__ h32, int t)
{
    __shared__ float red[8][16][66];
    const int tid = threadIdx.x;
    const int wv = tid >> 6, lane = tid & 63;
    const int row16 = lane & 15, kblk = lane >> 4;
    const int lid = blockIdx.x;
    const int rb = lid & 15, cb = lid >> 4;
    const int r0 = rb * 16, c0 = cb * 64;
    const size_t xcol = (size_t)wv * 32 + kblk * 8;

    f32x4 acc[4] = {};
    if (wv < 7) {
        const size_t xo = ((size_t)(r0 + row16) * TT + t) * II + xcol;
        short8 fxh = *(const short8*)(xh + xo);
        short8 fxl = *(const short8*)(xl + xo);
        #pragma unroll
        for (int n = 0; n < 4; ++n) {
            const size_t wo = (size_t)(c0 + n * 16 + row16) * II + xcol;
            short8 wiH = *(const short8*)(wihh + wo);
            short8 wiL = *(const short8*)(wihl + wo);
            acc[n] = MFMA(fxh, wiH, acc[n]);
            acc[n] = MFMA(fxh, wiL, acc[n]);
            acc[n] = MFMA(fxl, wiH, acc[n]);
        }
    }
    const size_t ha = (size_t)(r0 + row16) * HH + 128 * wv + kblk * 8;
    #pragma unroll
    for (int kb = 0; kb < 4; ++kb) {
        short8 fH = *(const short8*)(hph + ha + kb * 32);
        short8 fL = *(const short8*)(hpl + ha + kb * 32);
        #pragma unroll
        for (int n = 0; n < 4; ++n) {
            const size_t wo = (size_t)(c0 + n * 16 + row16) * HH + 128 * wv + kb * 32 + kblk * 8;
            short8 wH = *(const short8*)(whhh + wo);
            short8 wL = *(const short8*)(whhl + wo);
            acc[n] = MFMA(fH, wH, acc[n]);
            acc[n] = MFMA(fH, wL, acc[n]);
            acc[n] = MFMA(fL, wH, acc[n]);
        }
    }
    #pragma unroll
    for (int n = 0; n < 4; ++n)
        #pragma unroll
        for (int jj = 0; jj < 4; ++jj)
            red[wv][kblk * 4 + jj][n * 16 + row16] = acc[n][jj];
    __syncthreads();
    {
        const int cgl = c0 + lane;
        const int erow0 = wv * 2;
        float v0 = b_ih[cgl] + b_hh[cgl], v1 = v0;
        #pragma unroll
        for (int w = 0; w < 8; ++w) {
            v0 += red[w][erow0][lane];
            v1 += red[w][erow0 + 1][lane];
        }
        v0 = tanhf(v0); v1 = tanhf(v1);
        const size_t o = (size_t)(r0 + erow0) * HH + cgl;
        const unsigned short b0 = bfbits(v0), b1 = bfbits(v1);
        hnh[o] = b0;        hnh[o + HH] = b1;
        hnl[o] = bfbits(v0 - bffloat(b0));
        hnl[o + HH] = bfbits(v1 - bffloat(b1));
        if (t == TT - 1) { h32[o] = v0; h32[o + HH] = v1; }
    }
}

// ---------------------------------------------------------------- FC
__global__ __launch_bounds__(256) void fc_kernel(
    const float* __restrict__ h, const float* __restrict__ W_fc,
    const float* __restrict__ b_fc, float* __restrict__ out)
{
    const int b = blockIdx.x;
    const int tid = threadIdx.x;
    float p[OO] = {0.f, 0.f, 0.f, 0.f};
    for (int k = tid; k < HH; k += 256) {
        float hv = h[(size_t)b * HH + k];
        #pragma unroll
        for (int o = 0; o < OO; ++o) p[o] += hv * W_fc[(size_t)o * HH + k];
    }
    #pragma unroll
    for (int off = 32; off > 0; off >>= 1) {
        #pragma unroll
        for (int o = 0; o < OO; ++o) p[o] += __shfl_down(p[o], off, 64);
    }
    __shared__ float red[4][OO];
    const int wave = tid >> 6, lane = tid & 63;
    if (lane == 0) {
        #pragma unroll
        for (int o = 0; o < OO; ++o) red[wave][o] = p[o];
    }
    __syncthreads();
    if (tid < OO) {
        float s = red[0][tid] + red[1][tid] + red[2][tid] + red[3][tid] + b_fc[tid];
        out[b * OO + tid] = s;
    }
}

// ---------------------------------------------------------------- launch
extern "C" void kernel_launch(void* const* d_in, const int* in_sizes, int n_in,
                              void* d_out, int out_size, void* d_ws, size_t ws_size,
                              hipStream_t stream) {
    const float* x    = (const float*)d_in[0];
    const float* W_ih = (const float*)d_in[1];
    const float* W_hh = (const float*)d_in[2];
    const float* b_ih = (const float*)d_in[3];
    const float* b_hh = (const float*)d_in[4];
    const float* W_fc = (const float*)d_in[5];
    const float* b_fc = (const float*)d_in[6];
    float* out = (float*)d_out;

    // ws layout (bytes)
    const size_t SZ_X   = (size_t)BB * TT * II * 2;   // 25.7 MB per plane
    const size_t SZ_WIH = (size_t)HH * II * 2;
    const size_t SZ_WHH = (size_t)HH * HH * 2;
    const size_t SZ_H   = (size_t)BB * HH * 2;
    const size_t OFF_XH   = 0;
    const size_t OFF_XL   = OFF_XH + SZ_X;
    const size_t OFF_WIHH = OFF_XL + SZ_X;
    const size_t OFF_WIHL = OFF_WIHH + SZ_WIH;
    const size_t OFF_WHHH = OFF_WIHL + SZ_WIH;
    const size_t OFF_WHHL = OFF_WHHH + SZ_WHH;
    const size_t OFF_HAH  = OFF_WHHL + SZ_WHH;
    const size_t OFF_HAL  = OFF_HAH + SZ_H;
    const size_t OFF_HBH  = OFF_HAL + SZ_H;
    const size_t OFF_HBL  = OFF_HBH + SZ_H;
    const size_t OFF_H32  = OFF_HBL + SZ_H;
    const size_t OFF_FLAGS = OFF_H32 + (size_t)BB * HH * 4;
    const size_t NEED      = OFF_FLAGS + 256 * 64;

    char* ws = (char*)d_ws;

    if (ws_size >= NEED) {
        ushort_t* xhp  = (ushort_t*)(ws + OFF_XH);
        ushort_t* xlp  = (ushort_t*)(ws + OFF_XL);
        ushort_t* wihh = (ushort_t*)(ws + OFF_WIHH);
        ushort_t* wihl = (ushort_t*)(ws + OFF_WIHL);
        ushort_t* whhh = (ushort_t*)(ws + OFF_WHHH);
        ushort_t* whhl = (ushort_t*)(ws + OFF_WHHL);
        ushort_t* hAh  = (ushort_t*)(ws + OFF_HAH);
        ushort_t* hAl  = (ushort_t*)(ws + OFF_HAL);
        ushort_t* hBh  = (ushort_t*)(ws + OFF_HBH);
        ushort_t* hBl  = (ushort_t*)(ws + OFF_HBL);
        float*    h32  = (float*)(ws + OFF_H32);
        unsigned* flags = (unsigned*)(ws + OFF_FLAGS);

        // prep: hi/lo splits of x, W_ih, W_hh; zero h plane A + flags
        split_hi_lo<<<1024, 256, 0, stream>>>(x, xhp, xlp, (BB * TT * II) / 4);
        split_hi_lo<<<128, 256, 0, stream>>>(W_ih, wihh, wihl, (HH * II) / 4);
        split_hi_lo<<<512, 256, 0, stream>>>(W_hh, whhh, whhl, (HH * HH) / 4);
        zero_kernel<<<(int)((2 * SZ_H / 4 + 255) / 256), 256, 0, stream>>>((float*)(ws + OFF_HAH), (int)(2 * SZ_H / 4));
        zero_kernel<<<16, 256, 0, stream>>>((float*)flags, 4096);

        const float* bihp = b_ih;
        const float* bhhp = b_hh;
        void* args[] = {
            (void*)&xhp, (void*)&xlp, (void*)&wihh, (void*)&wihl,
            (void*)&whhh, (void*)&whhl,
            (void*)&hAh, (void*)&hAl, (void*)&hBh, (void*)&hBl,
            (void*)&bihp, (void*)&bhhp, (void*)&h32, (void*)&flags
        };
        hipError_t e = hipLaunchCooperativeKernel((void*)rnn_persist4,
                                                  dim3(256), dim3(512), args, 0, stream);
        if (e != hipSuccess) {
            // fallback: per-step loop (kernel boundaries provide coherence)
            for (int t = 0; t < TT; ++t) {
                const int p = t & 1;
                rnn_step_f<<<256, 512, 0, stream>>>(
                    xhp, xlp, wihh, wihl, whhh, whhl,
                    (p ? hBh : hAh), (p ? hBl : hAl),
                    (p ? hAh : hBh), (p ? hAl : hBl),
                    b_ih, b_hh, h32, t);
            }
        }
        fc_kernel<<<BB, 256, 0, stream>>>(h32, W_fc, b_fc, out);
    }
    // (ws too small not expected: NEED ~58 MB, observed ws ~268 MB)
}

// Round 12
// 1069.260 us; speedup vs baseline: 11.9710x; 1.0678x over previous
//
#include <hip/hip_runtime.h>
#include <hip/hip_bf16.h>
#include <cstddef>

#define BB 256
#define TT 224
#define II 224
#define HH 1024
#define OO 4

typedef __attribute__((ext_vector_type(8))) short short8;   // 8 bf16 (4 VGPRs)
typedef __attribute__((ext_vector_type(4))) float f32x4;    // MFMA accumulator
typedef unsigned short ushort_t;

// ---------------------------------------------------------------- helpers
__device__ __forceinline__ unsigned short bfbits(float v) {
    __hip_bfloat16 b = __float2bfloat16(v);
    union { __hip_bfloat16 b; unsigned short u; } cv; cv.b = b; return cv.u;
}
__device__ __forceinline__ float bffloat(unsigned short u) {
    union { unsigned short u; __hip_bfloat16 b; } cv; cv.u = u; return __bfloat162float(cv.b);
}

// asm VMEM: hot-loop VMEM is inline asm so counted vmcnt windows are exact.
#define LD128(d, p)      asm volatile("global_load_dwordx4 %0, %1, off" : "=v"(d) : "v"(p) : "memory")
#define LD128_SYS(d, p)  asm volatile("global_load_dwordx4 %0, %1, off sc0 sc1" : "=v"(d) : "v"(p) : "memory")
#define STD_SYS(p, v)    asm volatile("global_store_dword %0, %1, off sc0 sc1" :: "v"(p), "v"(v) : "memory")
#define WAIT_VM(n) do { asm volatile("s_waitcnt vmcnt(" #n ")" ::: "memory"); __builtin_amdgcn_sched_barrier(0); } while (0)

__device__ __forceinline__ void stflag(unsigned* p, unsigned v) {
    asm volatile("global_store_dword %0, %1, off sc0 sc1" :: "v"(p), "v"(v) : "memory");
}
__device__ __forceinline__ unsigned ldflag(const unsigned* p) {
    unsigned v;
    asm volatile("global_load_dword %0, %1, off sc0 sc1\n\ts_waitcnt vmcnt(0)"
                 : "=v"(v) : "v"(p) : "memory");
    return v;
}

// fast tanh: (1 - e^-2v)/(1 + e^-2v), clamped
__device__ __forceinline__ float fast_tanh(float v) {
    v = fminf(fmaxf(v, -15.f), 15.f);
    const float e = __expf(-2.f * v);
    return (1.f - e) * __builtin_amdgcn_rcpf(1.f + e);
}

#define MFMA(a, b, c) __builtin_amdgcn_mfma_f32_16x16x32_bf16(a, b, c, 0, 0, 0)

// ---------------------------------------------------------------- utility kernels
__global__ void zero_kernel(float* __restrict__ p, int n) {
    int i = blockIdx.x * blockDim.x + threadIdx.x;
    if (i < n) p[i] = 0.f;
}

__global__ __launch_bounds__(256) void split_hi_lo(
    const float* __restrict__ src, ushort_t* __restrict__ hi,
    ushort_t* __restrict__ lo, int n4)
{
    struct u4 { ushort_t v[4]; };
    const int stride = gridDim.x * blockDim.x;
    for (int i = blockIdx.x * blockDim.x + threadIdx.x; i < n4; i += stride) {
        float4 s = ((const float4*)src)[i];
        float vv[4] = {s.x, s.y, s.z, s.w};
        u4 h, l;
        #pragma unroll
        for (int j = 0; j < 4; ++j) {
            unsigned short hb = bfbits(vv[j]);
            h.v[j] = hb;
            l.v[j] = bfbits(vv[j] - bffloat(hb));
        }
        ((u4*)hi)[i] = h;
        ((u4*)lo)[i] = l;
    }
}

// ---------------------------------------------------------------- persistent RNN (R11 = R9 + micro-opts)
// 256 WGs (cooperative, 1/CU) x 512 thr (8 waves). 16 row-groups (16 rows) x
// 16 col-blocks (64 cols). Wave wv K-splits H into 128-slices; W_hh slice
// (128 VGPR) asm-staged into registers ONCE. x-projection folded in-step from
// pre-split bf16 planes. h exchange group-local via MALL (sc0 sc1) -> no
// fences, W regs / x L2 never disturbed. Per-wave 2-producer flag polls; the
// block's 8 waves collectively cover all 16 group flags before any epilogue
// store (WAR-safe at ping-pong distance). All loop VMEM inline asm (exact vmcnt).
// R11 deltas vs R9: x loads pre-poll; paired dword epilogue stores; setprio.
__global__ __launch_bounds__(512, 2) void rnn_persist4(
    const ushort_t* __restrict__ xh,   const ushort_t* __restrict__ xl,
    const ushort_t* __restrict__ wihh, const ushort_t* __restrict__ wihl,
    const ushort_t* __restrict__ whhh, const ushort_t* __restrict__ whhl,
    ushort_t* hAh, ushort_t* hAl, ushort_t* hBh, ushort_t* hBl,
    const float* __restrict__ b_ih, const float* __restrict__ b_hh,
    float* __restrict__ h32, unsigned* __restrict__ flags)
{
    __shared__ float red[8][16][66];   // 33.8 KB

    const int tid = threadIdx.x;
    const int wv = tid >> 6, lane = tid & 63;
    const int row16 = lane & 15, kblk = lane >> 4;
    const int lid = blockIdx.x;
    const int rb = lid & 15;           // row-group: rows 16*rb..+15
    const int cb = lid >> 4;           // col-block: cols 64*cb..+63
    const int r0 = rb * 16, c0 = cb * 64;

    // ---- stage W_hh K-slice into registers via asm loads (once) ----
    short8 wh[4][4], wl[4][4];         // [n][kb]
    #pragma unroll
    for (int n = 0; n < 4; ++n) {
        const ushort_t* bh = whhh + (size_t)(c0 + n * 16 + row16) * HH + 128 * wv + kblk * 8;
        const ushort_t* bl = whhl + (size_t)(c0 + n * 16 + row16) * HH + 128 * wv + kblk * 8;
        LD128(wh[n][0], bh);      LD128(wh[n][1], bh + 32);
        LD128(wh[n][2], bh + 64); LD128(wh[n][3], bh + 96);
        LD128(wl[n][0], bl);      LD128(wl[n][1], bl + 32);
        LD128(wl[n][2], bl + 64); LD128(wl[n][3], bl + 96);
    }
    WAIT_VM(0);

    // epilogue mapping: thread = (row erow, col-pair ecp): 1 row x 2 adjacent cols
    const int erow = tid >> 5;         // 0..15
    const int ecp  = tid & 31;         // 0..31
    const int cg0  = c0 + 2 * ecp;
    const float bias0 = b_ih[cg0] + b_hh[cg0];
    const float bias1 = b_ih[cg0 + 1] + b_hh[cg0 + 1];

    const size_t ha = (size_t)(r0 + row16) * HH + 128 * wv + kblk * 8;
    const size_t xrow = (size_t)(r0 + row16) * TT;
    const size_t xcol = (size_t)wv * 32 + kblk * 8;

    const int jprod = 2 * wv + (lane & 1);   // wave's 2 producers
    const unsigned* myflag = flags + ((size_t)jprod * 16 + rb) * 16;
    unsigned* ourflag = flags + (size_t)lid * 16;

    for (int t = 0; t < TT; ++t) {
        const ushort_t* hph = (t & 1) ? hBh : hAh;
        const ushort_t* hpl = (t & 1) ? hBl : hAl;
        ushort_t* hnh = (t & 1) ? hAh : hBh;
        ushort_t* hnl = (t & 1) ? hAl : hBl;

        // ---- issue x + W_ih loads early: latency hides under the poll
        short8 fxh{}, fxl{}, wih_[4], wil_[4];
        if (wv < 7) {
            LD128(fxh, xh + (xrow + t) * II + xcol);
            LD128(fxl, xl + (xrow + t) * II + xcol);
            #pragma unroll
            for (int n = 0; n < 4; ++n) {
                LD128(wih_[n], wihh + (size_t)(c0 + n * 16 + row16) * II + xcol);
                LD128(wil_[n], wihl + (size_t)(c0 + n * 16 + row16) * II + xcol);
            }
        }

        // ---- per-wave poll: producers of our K-chunks set flag = t after step t-1
        if (t) {
            while (true) {
                unsigned vf = ldflag(myflag);   // embedded vmcnt(0) also drains x loads
                if (__ballot(vf >= (unsigned)t) == ~0ull) break;
                __builtin_amdgcn_s_sleep(1);
            }
        }

        // ---- h loads, system scope (MALL)
        short8 fh[4], fl[4];
        {
            const ushort_t* ph = hph + ha;
            const ushort_t* pl = hpl + ha;
            LD128_SYS(fh[0], ph);      LD128_SYS(fl[0], pl);
            LD128_SYS(fh[1], ph + 32); LD128_SYS(fl[1], pl + 32);
            LD128_SYS(fh[2], ph + 64); LD128_SYS(fl[2], pl + 64);
            LD128_SYS(fh[3], ph + 96); LD128_SYS(fl[3], pl + 96);
        }

        f32x4 acc[4] = {};
        // ---- x-projection MFMAs overlap the h sys-load latency
        if (wv < 7) {
            WAIT_VM(8);    // x-side loads complete; 8 h loads outstanding
            #pragma unroll
            for (int n = 0; n < 4; ++n) {
                acc[n] = MFMA(fxh, wih_[n], acc[n]);
                acc[n] = MFMA(fxh, wil_[n], acc[n]);
                acc[n] = MFMA(fxl, wih_[n], acc[n]);
            }
        }
        __builtin_amdgcn_s_setprio(1);
        WAIT_VM(4);        // fh/fl kb0,kb1 ready
        #pragma unroll
        for (int kb = 0; kb < 2; ++kb)
            #pragma unroll
            for (int n = 0; n < 4; ++n) {
                acc[n] = MFMA(fh[kb], wh[n][kb], acc[n]);
                acc[n] = MFMA(fh[kb], wl[n][kb], acc[n]);
                acc[n] = MFMA(fl[kb], wh[n][kb], acc[n]);
            }
        WAIT_VM(0);        // kb2,kb3 ready
        #pragma unroll
        for (int kb = 2; kb < 4; ++kb)
            #pragma unroll
            for (int n = 0; n < 4; ++n) {
                acc[n] = MFMA(fh[kb], wh[n][kb], acc[n]);
                acc[n] = MFMA(fh[kb], wl[n][kb], acc[n]);
                acc[n] = MFMA(fl[kb], wh[n][kb], acc[n]);
            }
        __builtin_amdgcn_s_setprio(0);

        // ---- cross-wave K reduction
        #pragma unroll
        for (int n = 0; n < 4; ++n)
            #pragma unroll
            for (int jj = 0; jj < 4; ++jj)
                red[wv][kblk * 4 + jj][n * 16 + row16] = acc[n][jj];
        __syncthreads();

        // ---- epilogue: 1 row x 2 cols per thread, packed dword stores
        {
            float v0 = bias0, v1 = bias1;
            #pragma unroll
            for (int w = 0; w < 8; ++w) {
                float2 rv = *(const float2*)&red[w][erow][2 * ecp];
                v0 += rv.x; v1 += rv.y;
            }
            v0 = fast_tanh(v0);
            v1 = fast_tanh(v1);
            const size_t o = (size_t)(r0 + erow) * HH + cg0;
            const unsigned short h0 = bfbits(v0), h1 = bfbits(v1);
            const unsigned packh = (unsigned)h0 | ((unsigned)h1 << 16);
            const unsigned short l0 = bfbits(v0 - bffloat(h0));
            const unsigned short l1 = bfbits(v1 - bffloat(h1));
            const unsigned packl = (unsigned)l0 | ((unsigned)l1 << 16);
            STD_SYS(hnh + o, packh);
            STD_SYS(hnl + o, packl);
            if (t == TT - 1) { h32[o] = v0; h32[o + 1] = v1; }
        }

        WAIT_VM(0);        // stores acked at MALL
        __syncthreads();   // all waves stored; also protects red reuse
        if (tid == 0) stflag(ourflag, (unsigned)(t + 1));
    }
}

// ---------------------------------------------------------------- per-step fallback (coop launch fail)
__global__ __launch_bounds__(512) void rnn_step_f(
    const ushort_t* __restrict__ xh,   const ushort_t* __restrict__ xl,
    const ushort_t* __restrict__ wihh, const ushort_t* __restrict__ wihl,
    const ushort_t* __restrict__ whhh, const ushort_t* __restrict__ whhl,
    const ushort_t* __restrict__ hph,  const ushort_t* __restrict__ hpl,
    ushort_t* __restrict__ hnh, ushort_t* __restrict__ hnl,
    const float* __restrict__ b_ih, const float* __restrict__ b_hh,
    float* __restrict__ h32, int t)
{
    __shared__ float red[8][16][66];
    const int tid = threadIdx.x;
    const int wv = tid >> 6, lane = tid & 63;
    const int row16 = lane & 15, kblk = lane >> 4;
    const int lid = blockIdx.x;
    const int rb = lid & 15, cb = lid >> 4;
    const int r0 = rb * 16, c0 = cb * 64;
    const size_t xcol = (size_t)wv * 32 + kblk * 8;

    f32x4 acc[4] = {};
    if (wv < 7) {
        const size_t xo = ((size_t)(r0 + row16) * TT + t) * II + xcol;
        short8 fxh = *(const short8*)(xh + xo);
        short8 fxl = *(const short8*)(xl + xo);
        #pragma unroll
        for (int n = 0; n < 4; ++n) {
            const size_t wo = (size_t)(c0 + n * 16 + row16) * II + xcol;
            short8 wiH = *(const short8*)(wihh + wo);
            short8 wiL = *(const short8*)(wihl + wo);
            acc[n] = MFMA(fxh, wiH, acc[n]);
            acc[n] = MFMA(fxh, wiL, acc[n]);
            acc[n] = MFMA(fxl, wiH, acc[n]);
        }
    }
    const size_t ha = (size_t)(r0 + row16) * HH + 128 * wv + kblk * 8;
    #pragma unroll
    for (int kb = 0; kb < 4; ++kb) {
        short8 fH = *(const short8*)(hph + ha + kb * 32);
        short8 fL = *(const short8*)(hpl + ha + kb * 32);
        #pragma unroll
        for (int n = 0; n < 4; ++n) {
            const size_t wo = (size_t)(c0 + n * 16 + row16) * HH + 128 * wv + kb * 32 + kblk * 8;
            short8 wH = *(const short8*)(whhh + wo);
            short8 wL = *(const short8*)(whhl + wo);
            acc[n] = MFMA(fH, wH, acc[n]);
            acc[n] = MFMA(fH, wL, acc[n]);
            acc[n] = MFMA(fL, wH, acc[n]);
        }
    }
    #pragma unroll
    for (int n = 0; n < 4; ++n)
        #pragma unroll
        for (int jj = 0; jj < 4; ++jj)
            red[wv][kblk * 4 + jj][n * 16 + row16] = acc[n][jj];
    __syncthreads();
    {
        const int erow = tid >> 5;
        const int ecp  = tid & 31;
        const int cg0  = c0 + 2 * ecp;
        float v0 = b_ih[cg0] + b_hh[cg0];
        float v1 = b_ih[cg0 + 1] + b_hh[cg0 + 1];
        #pragma unroll
        for (int w = 0; w < 8; ++w) {
            float2 rv = *(const float2*)&red[w][erow][2 * ecp];
            v0 += rv.x; v1 += rv.y;
        }
        v0 = tanhf(v0); v1 = tanhf(v1);
        const size_t o = (size_t)(r0 + erow) * HH + cg0;
        const unsigned short h0 = bfbits(v0), h1 = bfbits(v1);
        hnh[o] = h0;  hnh[o + 1] = h1;
        hnl[o] = bfbits(v0 - bffloat(h0));
        hnl[o + 1] = bfbits(v1 - bffloat(h1));
        if (t == TT - 1) { h32[o] = v0; h32[o + 1] = v1; }
    }
}

// ---------------------------------------------------------------- FC
__global__ __launch_bounds__(256) void fc_kernel(
    const float* __restrict__ h, const float* __restrict__ W_fc,
    const float* __restrict__ b_fc, float* __restrict__ out)
{
    const int b = blockIdx.x;
    const int tid = threadIdx.x;
    float p[OO] = {0.f, 0.f, 0.f, 0.f};
    for (int k = tid; k < HH; k += 256) {
        float hv = h[(size_t)b * HH + k];
        #pragma unroll
        for (int o = 0; o < OO; ++o) p[o] += hv * W_fc[(size_t)o * HH + k];
    }
    #pragma unroll
    for (int off = 32; off > 0; off >>= 1) {
        #pragma unroll
        for (int o = 0; o < OO; ++o) p[o] += __shfl_down(p[o], off, 64);
    }
    __shared__ float red[4][OO];
    const int wave = tid >> 6, lane = tid & 63;
    if (lane == 0) {
        #pragma unroll
        for (int o = 0; o < OO; ++o) red[wave][o] = p[o];
    }
    __syncthreads();
    if (tid < OO) {
        float s = red[0][tid] + red[1][tid] + red[2][tid] + red[3][tid] + b_fc[tid];
        out[b * OO + tid] = s;
    }
}

// ---------------------------------------------------------------- launch
extern "C" void kernel_launch(void* const* d_in, const int* in_sizes, int n_in,
                              void* d_out, int out_size, void* d_ws, size_t ws_size,
                              hipStream_t stream) {
    const float* x    = (const float*)d_in[0];
    const float* W_ih = (const float*)d_in[1];
    const float* W_hh = (const float*)d_in[2];
    const float* b_ih = (const float*)d_in[3];
    const float* b_hh = (const float*)d_in[4];
    const float* W_fc = (const float*)d_in[5];
    const float* b_fc = (const float*)d_in[6];
    float* out = (float*)d_out;

    // ws layout (bytes)
    const size_t SZ_X   = (size_t)BB * TT * II * 2;   // 25.7 MB per plane
    const size_t SZ_WIH = (size_t)HH * II * 2;
    const size_t SZ_WHH = (size_t)HH * HH * 2;
    const size_t SZ_H   = (size_t)BB * HH * 2;
    const size_t OFF_XH   = 0;
    const size_t OFF_XL   = OFF_XH + SZ_X;
    const size_t OFF_WIHH = OFF_XL + SZ_X;
    const size_t OFF_WIHL = OFF_WIHH + SZ_WIH;
    const size_t OFF_WHHH = OFF_WIHL + SZ_WIH;
    const size_t OFF_WHHL = OFF_WHHH + SZ_WHH;
    const size_t OFF_HAH  = OFF_WHHL + SZ_WHH;
    const size_t OFF_HAL  = OFF_HAH + SZ_H;
    const size_t OFF_HBH  = OFF_HAL + SZ_H;
    const size_t OFF_HBL  = OFF_HBH + SZ_H;
    const size_t OFF_H32  = OFF_HBL + SZ_H;
    const size_t OFF_FLAGS = OFF_H32 + (size_t)BB * HH * 4;
    const size_t NEED      = OFF_FLAGS + 256 * 64;

    char* ws = (char*)d_ws;

    if (ws_size >= NEED) {
        ushort_t* xhp  = (ushort_t*)(ws + OFF_XH);
        ushort_t* xlp  = (ushort_t*)(ws + OFF_XL);
        ushort_t* wihh = (ushort_t*)(ws + OFF_WIHH);
        ushort_t* wihl = (ushort_t*)(ws + OFF_WIHL);
        ushort_t* whhh = (ushort_t*)(ws + OFF_WHHH);
        ushort_t* whhl = (ushort_t*)(ws + OFF_WHHL);
        ushort_t* hAh  = (ushort_t*)(ws + OFF_HAH);
        ushort_t* hAl  = (ushort_t*)(ws + OFF_HAL);
        ushort_t* hBh  = (ushort_t*)(ws + OFF_HBH);
        ushort_t* hBl  = (ushort_t*)(ws + OFF_HBL);
        float*    h32  = (float*)(ws + OFF_H32);
        unsigned* flags = (unsigned*)(ws + OFF_FLAGS);

        // prep: hi/lo splits of x, W_ih, W_hh; zero h plane A + flags
        split_hi_lo<<<1024, 256, 0, stream>>>(x, xhp, xlp, (BB * TT * II) / 4);
        split_hi_lo<<<128, 256, 0, stream>>>(W_ih, wihh, wihl, (HH * II) / 4);
        split_hi_lo<<<512, 256, 0, stream>>>(W_hh, whhh, whhl, (HH * HH) / 4);
        zero_kernel<<<(int)((2 * SZ_H / 4 + 255) / 256), 256, 0, stream>>>((float*)(ws + OFF_HAH), (int)(2 * SZ_H / 4));
        zero_kernel<<<16, 256, 0, stream>>>((float*)flags, 4096);

        const float* bihp = b_ih;
        const float* bhhp = b_hh;
        void* args[] = {
            (void*)&xhp, (void*)&xlp, (void*)&wihh, (void*)&wihl,
            (void*)&whhh, (void*)&whhl,
            (void*)&hAh, (void*)&hAl, (void*)&hBh, (void*)&hBl,
            (void*)&bihp, (void*)&bhhp, (void*)&h32, (void*)&flags
        };
        hipError_t e = hipLaunchCooperativeKernel((void*)rnn_persist4,
                                                  dim3(256), dim3(512), args, 0, stream);
        if (e != hipSuccess) {
            // fallback: per-step loop (kernel boundaries provide coherence)
            for (int t = 0; t < TT; ++t) {
                const int p = t & 1;
                rnn_step_f<<<256, 512, 0, stream>>>(
                    xhp, xlp, wihh, wihl, whhh, whhl,
                    (p ? hBh : hAh), (p ? hBl : hAl),
                    (p ? hAh : hBh), (p ? hAl : hBl),
                    b_ih, b_hh, h32, t);
            }
        }
        fc_kernel<<<BB, 256, 0, stream>>>(h32, W_fc, b_fc, out);
    }
    // (ws too small not expected: NEED ~58 MB, observed ws ~268 MB)
}